// Round 2
// baseline (1451.825 us; speedup 1.0000x reference)
//
#include <hip/hip_runtime.h>
#include <math.h>

#define B_   4096
#define DZ   128
#define DF   2048
#define N2   8192            // 2*B_
#define NL   8191            // 2*B_ - 1

// d_out layout (floats): [loss(1)][logits(8192*8191)][labels(8192)][lids32(8192)][lids512(8192)]
#define OFF_LOGITS 1
#define OFF_LAB  (1 + (size_t)N2 * NL)      // 67100673
#define OFF_L32  (OFF_LAB + N2)             // 67108865
#define OFF_L512 (OFF_L32 + N2)             // 67117057
// D2 scratch overlays d_out[0 .. N2*N2) = [0, 67108864) — disjoint from lids slots.

// ws layout (floats)
#define WS_ZN 0
#define WS_FN ((size_t)N2 * DZ)             // 1048576
#define WS_LP (WS_FN + N2)
#define WS_FCOMB (WS_LP + N2)               // bf16 hi/lo precomp: N2*DF floats (= N2*DF*2 shorts)

typedef __attribute__((ext_vector_type(8))) __bf16 bf16x8;
typedef __attribute__((ext_vector_type(8))) unsigned short ushort8;
typedef __attribute__((ext_vector_type(4))) float f32x4;

// round-to-nearest-even fp32 -> bf16 bits (inputs are finite Gaussians; no NaN path needed)
__device__ __forceinline__ unsigned short f2bf(float f) {
  unsigned u = __float_as_uint(f);
  return (unsigned short)((u + 0x7FFFu + ((u >> 16) & 1u)) >> 16);
}
__device__ __forceinline__ float bf2f(unsigned short h) {
  return __uint_as_float(((unsigned)h) << 16);
}

// ---------------- row norms of f (||f_i||^2) — fallback path only ----------------
__global__ __launch_bounds__(256) void fnorm_kernel(const float* __restrict__ f0,
                                                    const float* __restrict__ f1,
                                                    float* __restrict__ fn) {
  int r = blockIdx.x;
  const float* row = (r < B_) ? f0 + (size_t)r * DF : f1 + (size_t)(r - B_) * DF;
  float s = 0.f;
  for (int j = threadIdx.x; j < DF; j += 256) { float v = row[j]; s += v * v; }
  for (int off = 32; off; off >>= 1) s += __shfl_down(s, off, 64);
  __shared__ float red[4];
  if ((threadIdx.x & 63) == 0) red[threadIdx.x >> 6] = s;
  __syncthreads();
  if (threadIdx.x == 0) fn[r] = red[0] + red[1] + red[2] + red[3];
}

// ---------------- fused: fp32 -> bf16 hi/lo precompute + row norms ----------------
// fcomb layout per row r: 64 slabs x 128 B; slab s = [hi(32 shorts) | lo(32 shorts)]
// covering k = s*32 .. s*32+32. Row byte stride = 8192.
__global__ __launch_bounds__(256) void convert_kernel(const float* __restrict__ f0,
                                                      const float* __restrict__ f1,
                                                      unsigned short* __restrict__ fcomb,
                                                      float* __restrict__ fn) {
  int r = blockIdx.x, t = threadIdx.x;
  const float* row = (r < B_) ? f0 + (size_t)r * DF : f1 + (size_t)(r - B_) * DF;
  float4 v0 = *(const float4*)(row + t * 8);
  float4 v1 = *(const float4*)(row + t * 8 + 4);
  float v[8] = {v0.x, v0.y, v0.z, v0.w, v1.x, v1.y, v1.z, v1.w};
  ushort8 h, l;
  float s = 0.f;
#pragma unroll
  for (int j = 0; j < 8; j++) {
    unsigned short hb = f2bf(v[j]);
    h[j] = hb;
    l[j] = f2bf(v[j] - bf2f(hb));
    s += v[j] * v[j];
  }
  unsigned short* rowp = fcomb + (size_t)r * (2 * DF);
  int slab = t >> 2, c = t & 3;           // thread covers hi chunk c, lo chunk 4+c of slab
  *(ushort8*)(rowp + slab * 64 + c * 8) = h;
  *(ushort8*)(rowp + slab * 64 + 32 + c * 8) = l;
  for (int off = 32; off; off >>= 1) s += __shfl_down(s, off, 64);
  __shared__ float red[4];
  if ((t & 63) == 0) red[t >> 6] = s;
  __syncthreads();
  if (t == 0) fn[r] = red[0] + red[1] + red[2] + red[3];
}

// ---------------- normalize z rows ----------------
__global__ void znorm_kernel(const float* __restrict__ z0, const float* __restrict__ z1,
                             float* __restrict__ zn) {
  int r = blockIdx.x, t = threadIdx.x;  // 128 threads
  const float* row = (r < B_) ? z0 + (size_t)r * DZ : z1 + (size_t)(r - B_) * DZ;
  float v = row[t];
  float s = v * v;
  for (int off = 32; off; off >>= 1) s += __shfl_down(s, off, 64);
  __shared__ float red[2];
  if ((t & 63) == 0) red[t >> 6] = s;
  __syncthreads();
  float n = sqrtf(red[0] + red[1]);
  zn[(size_t)r * DZ + t] = v / fmaxf(n, 1e-12f);
}

// ---------------- D2 GEMM from precomputed bf16 hi/lo, global_load_lds staging ----------------
// 128x128 tile, 4 waves (2x2 quadrants of 4x4 16x16 MFMA tiles), 3 passes (hh+hl+lh).
// LDS: TILE = A2[128][64 shorts] ++ B2[128][64 shorts] = 32 KB, linear (no pad).
// Swizzle (rule 21, both-sides): 16B-chunk index x at row r holds data chunk x^(r&7);
// applied on the per-lane GLOBAL source address at stage time and on the ds_read address.
__global__ __launch_bounds__(256) void d2_gemm_pre_kernel(const unsigned short* __restrict__ fcomb,
                                                          const float* __restrict__ fn,
                                                          float* __restrict__ D2) {
  int bj = blockIdx.x, bi = blockIdx.y;
  if (bi > bj) return;
  const int ib = bi * 128, jb = bj * 128;

  __shared__ __attribute__((aligned(16))) unsigned short TILE[2 * 128 * 64];

  const int tid = threadIdx.x;
  const int lane = tid & 63;
  const int wave = tid >> 6;
  const int wr = (wave >> 1) * 64;     // quadrant row base within tile
  const int wc = (wave & 1) * 64;      // quadrant col base within tile
  const int m  = lane & 15;            // frag row/col within 16
  const int kg = lane >> 4;            // k-group (0..3) -> k = kg*8 + j

  // staging: wave w covers LDS bytes [w*8192, (w+1)*8192): w0/w1 = A rows 0-63/64-127, w2/w3 = B.
  const int lrow8 = lane >> 3;                 // 0..7: row within 8-row stripe
  const int lchk  = (lane & 7) ^ lrow8;        // inverse-swizzled source chunk
  const int grow0 = ((wave < 2) ? ib : jb) + (wave & 1) * 64;
  const char* gsrc = (const char*)fcomb + (size_t)(grow0 + lrow8) * 8192 + (size_t)lchk * 16;
  char* lds0 = (char*)&TILE[0] + wave * 8192;

  f32x4 acc[4][4];
#pragma unroll
  for (int i = 0; i < 4; i++)
#pragma unroll
    for (int j = 0; j < 4; j++) acc[i][j] = (f32x4)0.f;

  for (int s = 0; s < 64; ++s, gsrc += 128) {
#pragma unroll
    for (int i = 0; i < 8; i++) {
      __builtin_amdgcn_global_load_lds(
          (const __attribute__((address_space(1))) void*)(gsrc + (size_t)i * 65536),
          (__attribute__((address_space(3))) void*)(lds0 + i * 1024), 16, 0, 0);
    }
    __syncthreads();   // drains vmcnt(0): staged slab visible to all waves

    bf16x8 a_h[4], a_l[4], b_h[4], b_l[4];
#pragma unroll
    for (int t4 = 0; t4 < 4; t4++) {
      int ra = wr + t4 * 16 + m;
      int rb = wc + t4 * 16 + m;
      int sa = ra & 7, sb = rb & 7;
      a_h[t4] = *(const bf16x8*)&TILE[ra * 64 + ((kg ^ sa) << 3)];
      a_l[t4] = *(const bf16x8*)&TILE[ra * 64 + (((kg | 4) ^ sa) << 3)];
      b_h[t4] = *(const bf16x8*)&TILE[8192 + rb * 64 + ((kg ^ sb) << 3)];
      b_l[t4] = *(const bf16x8*)&TILE[8192 + rb * 64 + (((kg | 4) ^ sb) << 3)];
    }
#pragma unroll
    for (int ti = 0; ti < 4; ti++)
#pragma unroll
      for (int tj = 0; tj < 4; tj++) {
        acc[ti][tj] = __builtin_amdgcn_mfma_f32_16x16x32_bf16(a_h[ti], b_h[tj], acc[ti][tj], 0, 0, 0);
        acc[ti][tj] = __builtin_amdgcn_mfma_f32_16x16x32_bf16(a_h[ti], b_l[tj], acc[ti][tj], 0, 0, 0);
        acc[ti][tj] = __builtin_amdgcn_mfma_f32_16x16x32_bf16(a_l[ti], b_h[tj], acc[ti][tj], 0, 0, 0);
      }
    __syncthreads();   // frag reads done before next slab's stores land
  }

  // epilogue: D2[i][j] = max(fn[i]+fn[j]-2*dot, 0); direct + mirror stores
  // C/D layout: col = lane&15, row = (lane>>4)*4 + reg
#pragma unroll
  for (int ti = 0; ti < 4; ti++) {
    int irow0 = ib + wr + ti * 16 + kg * 4;
    float4 fni = *(const float4*)&fn[irow0];
    float fniv[4] = {fni.x, fni.y, fni.z, fni.w};
#pragma unroll
    for (int tj = 0; tj < 4; tj++) {
      int jg = jb + wc + tj * 16 + m;
      float fnj = fn[jg];
      float val[4];
#pragma unroll
      for (int r = 0; r < 4; r++)
        val[r] = fmaxf(fniv[r] + fnj - 2.f * acc[ti][tj][r], 0.f);
#pragma unroll
      for (int r = 0; r < 4; r++)
        D2[(size_t)(irow0 + r) * N2 + jg] = val[r];
      if (bi != bj)
        *(float4*)&D2[(size_t)jg * N2 + irow0] = make_float4(val[0], val[1], val[2], val[3]);
    }
  }
}

// ---------------- D2 via bf16 hi/lo split MFMA (fallback if ws too small) ----------------
#define LSTR 40   // padded LDS row stride in shorts (80 B)
__global__ __launch_bounds__(256) void d2_gemm_mfma_kernel(const float* __restrict__ f0,
                                                           const float* __restrict__ f1,
                                                           const float* __restrict__ fn,
                                                           float* __restrict__ D2) {
  int bj = blockIdx.x, bi = blockIdx.y;
  if (bi > bj) return;
  const int ib = bi * 128, jb = bj * 128;
  const float* Ab = (ib < B_) ? f0 + (size_t)ib * DF : f1 + (size_t)(ib - B_) * DF;
  const float* Bb = (jb < B_) ? f0 + (size_t)jb * DF : f1 + (size_t)(jb - B_) * DF;

  __shared__ __attribute__((aligned(16))) unsigned short Ah[128 * LSTR];
  __shared__ __attribute__((aligned(16))) unsigned short Al[128 * LSTR];
  __shared__ __attribute__((aligned(16))) unsigned short Bh[128 * LSTR];
  __shared__ __attribute__((aligned(16))) unsigned short Bl[128 * LSTR];

  const int tid = threadIdx.x;
  const int lane = tid & 63;
  const int wave = tid >> 6;
  const int wr = (wave >> 1) * 64;
  const int wc = (wave & 1) * 64;
  const int m  = lane & 15;
  const int kg = lane >> 4;

  const int lrow = tid >> 1;
  const int lhalf = tid & 1;
  const float* arow = Ab + (size_t)lrow * DF + lhalf * 16;
  const float* brow = Bb + (size_t)lrow * DF + lhalf * 16;
  const int wbase = lrow * LSTR + lhalf * 16;

  f32x4 acc[4][4];
#pragma unroll
  for (int i = 0; i < 4; i++)
#pragma unroll
    for (int j = 0; j < 4; j++) acc[i][j] = (f32x4)0.f;

  for (int k0 = 0; k0 < DF; k0 += 32) {
    float av[16], bv[16];
#pragma unroll
    for (int q = 0; q < 4; q++) {
      float4 t = *(const float4*)(arow + k0 + q * 4);
      av[q * 4 + 0] = t.x; av[q * 4 + 1] = t.y; av[q * 4 + 2] = t.z; av[q * 4 + 3] = t.w;
    }
#pragma unroll
    for (int q = 0; q < 4; q++) {
      float4 t = *(const float4*)(brow + k0 + q * 4);
      bv[q * 4 + 0] = t.x; bv[q * 4 + 1] = t.y; bv[q * 4 + 2] = t.z; bv[q * 4 + 3] = t.w;
    }

    __syncthreads();

    ushort8 ah0, ah1, al0, al1, bh0, bh1, bl0, bl1;
#pragma unroll
    for (int j = 0; j < 8; j++) {
      unsigned short h = f2bf(av[j]);     ah0[j] = h; al0[j] = f2bf(av[j] - bf2f(h));
      unsigned short h2 = f2bf(av[j + 8]); ah1[j] = h2; al1[j] = f2bf(av[j + 8] - bf2f(h2));
      unsigned short h3 = f2bf(bv[j]);     bh0[j] = h3; bl0[j] = f2bf(bv[j] - bf2f(h3));
      unsigned short h4 = f2bf(bv[j + 8]); bh1[j] = h4; bl1[j] = f2bf(bv[j + 8] - bf2f(h4));
    }
    *(ushort8*)&Ah[wbase] = ah0;     *(ushort8*)&Ah[wbase + 8] = ah1;
    *(ushort8*)&Al[wbase] = al0;     *(ushort8*)&Al[wbase + 8] = al1;
    *(ushort8*)&Bh[wbase] = bh0;     *(ushort8*)&Bh[wbase + 8] = bh1;
    *(ushort8*)&Bl[wbase] = bl0;     *(ushort8*)&Bl[wbase + 8] = bl1;

    __syncthreads();

    bf16x8 a_h[4], a_l[4], b_h[4], b_l[4];
#pragma unroll
    for (int t4 = 0; t4 < 4; t4++) {
      int aoff = (wr + t4 * 16 + m) * LSTR + kg * 8;
      int boff = (wc + t4 * 16 + m) * LSTR + kg * 8;
      a_h[t4] = *(const bf16x8*)&Ah[aoff];
      a_l[t4] = *(const bf16x8*)&Al[aoff];
      b_h[t4] = *(const bf16x8*)&Bh[boff];
      b_l[t4] = *(const bf16x8*)&Bl[boff];
    }
#pragma unroll
    for (int ti = 0; ti < 4; ti++)
#pragma unroll
      for (int tj = 0; tj < 4; tj++) {
        acc[ti][tj] = __builtin_amdgcn_mfma_f32_16x16x32_bf16(a_h[ti], b_h[tj], acc[ti][tj], 0, 0, 0);
        acc[ti][tj] = __builtin_amdgcn_mfma_f32_16x16x32_bf16(a_h[ti], b_l[tj], acc[ti][tj], 0, 0, 0);
        acc[ti][tj] = __builtin_amdgcn_mfma_f32_16x16x32_bf16(a_l[ti], b_h[tj], acc[ti][tj], 0, 0, 0);
      }
  }

#pragma unroll
  for (int ti = 0; ti < 4; ti++) {
    int irow0 = ib + wr + ti * 16 + kg * 4;
    float4 fni = *(const float4*)&fn[irow0];
    float fniv[4] = {fni.x, fni.y, fni.z, fni.w};
#pragma unroll
    for (int tj = 0; tj < 4; tj++) {
      int jg = jb + wc + tj * 16 + m;
      float fnj = fn[jg];
      float val[4];
#pragma unroll
      for (int r = 0; r < 4; r++)
        val[r] = fmaxf(fniv[r] + fnj - 2.f * acc[ti][tj][r], 0.f);
#pragma unroll
      for (int r = 0; r < 4; r++)
        D2[(size_t)(irow0 + r) * N2 + jg] = val[r];
      if (bi != bj)
        *(float4*)&D2[(size_t)jg * N2 + irow0] = make_float4(val[0], val[1], val[2], val[3]);
    }
  }
}

// ---------------- per-row LID via dual threshold (no sort) ----------------
// LID_k = -k / S_k with S_k = sum_{i=1..k} log(d_i/d_k + eps) over the sorted 513
// smallest (rank 0 = self). Key facts: (1) bit-descent T(L) = max{x: count(<x) <= L}
// equals the (L+1)-th smallest key exactly; (2) the S_k sum is order-independent:
// ranks 1..k = {keys < T(k)} \ {min} plus copies of T(k), and a T-tie term is
// logf(1 + 1e-12f) == 0.0f in fp32. So: sum logs over keys<T, subtract the min term.
// This replaces prefix-scan + gather + 45-stage bitonic sort (~61 syncthreads).
__global__ __launch_bounds__(256) void select_lid_kernel(const float* __restrict__ D2,
                                                         float* __restrict__ out) {
  int r = blockIdx.x, tid = threadIdx.x;
  const float* row = D2 + (size_t)r * N2;
  unsigned key[32];
#pragma unroll
  for (int j = 0; j < 8; j++) {
    float4 v = *(const float4*)(row + tid * 4 + (size_t)j * 1024);
    key[j * 4 + 0] = __float_as_uint(fmaxf(v.x, 0.f));
    key[j * 4 + 1] = __float_as_uint(fmaxf(v.y, 0.f));
    key[j * 4 + 2] = __float_as_uint(fmaxf(v.z, 0.f));
    key[j * 4 + 3] = __float_as_uint(fmaxf(v.w, 0.f));
  }

  __shared__ int wcnt[31][2][4];
  __shared__ unsigned umin[4];
  __shared__ float red[8];

  // block-min (the self key; dropped from the sums at the end)
  unsigned kmin = 0xFFFFFFFFu;
#pragma unroll
  for (int j = 0; j < 32; j++) kmin = min(kmin, key[j]);
  for (int off = 32; off; off >>= 1) kmin = min(kmin, (unsigned)__shfl_down((int)kmin, off, 64));
  if ((tid & 63) == 0) umin[tid >> 6] = kmin;

  // fused dual bit-descent: T32 = 33rd smallest, T512 = 513th smallest
  unsigned T32 = 0, T512 = 0;
  for (int b = 30; b >= 0; b--) {
    unsigned t32 = T32 | (1u << b), t512 = T512 | (1u << b);
    int c32 = 0, c512 = 0;
#pragma unroll
    for (int j = 0; j < 32; j++) {
      c32 += (key[j] < t32) ? 1 : 0;
      c512 += (key[j] < t512) ? 1 : 0;
    }
    for (int off = 32; off; off >>= 1) {
      c32 += __shfl_down(c32, off, 64);
      c512 += __shfl_down(c512, off, 64);
    }
    if ((tid & 63) == 0) { wcnt[b][0][tid >> 6] = c32; wcnt[b][1][tid >> 6] = c512; }
    __syncthreads();
    if (wcnt[b][0][0] + wcnt[b][0][1] + wcnt[b][0][2] + wcnt[b][0][3] <= 32)  T32 = t32;
    if (wcnt[b][1][0] + wcnt[b][1][1] + wcnt[b][1][2] + wcnt[b][1][3] <= 512) T512 = t512;
  }
  kmin = min(min(umin[0], umin[1]), min(umin[2], umin[3]));

  // predicated log-sums over {key < T}; ties at T contribute exactly 0
  float d32 = sqrtf(__uint_as_float(T32));
  float d512 = sqrtf(__uint_as_float(T512));
  float s32 = 0.f, s512 = 0.f;
#pragma unroll
  for (int j = 0; j < 32; j++) {
    if (key[j] < T512) {
      float d = sqrtf(__uint_as_float(key[j]));
      s512 += logf(d / d512 + 1e-12f);
      if (key[j] < T32) s32 += logf(d / d32 + 1e-12f);
    }
  }
  for (int off = 32; off; off >>= 1) {
    s32 += __shfl_down(s32, off, 64);
    s512 += __shfl_down(s512, off, 64);
  }
  if ((tid & 63) == 0) { red[tid >> 6] = s32; red[4 + (tid >> 6)] = s512; }
  __syncthreads();
  if (tid == 0) {
    float dmin = sqrtf(__uint_as_float(kmin));
    float S32 = red[0] + red[1] + red[2] + red[3] - logf(dmin / d32 + 1e-12f);
    float S512 = red[4] + red[5] + red[6] + red[7] - logf(dmin / d512 + 1e-12f);
    out[OFF_L32 + r] = -32.f / S32;
    out[OFF_L512 + r] = -512.f / S512;
  }
}

// ---------------- logits = reshuffled z-gram / T (symmetric: lower triangle + mirror) ----------------
__device__ __forceinline__ void store_logit(float* __restrict__ out, int R, int C, float lg) {
  int col;
  if (R < B_) col = (C >= B_) ? (C - B_) : (B_ + C - (C > R ? 1 : 0));
  else        col = (C < B_) ? C : (C - (C > R ? 1 : 0));
  out[OFF_LOGITS + (size_t)R * NL + col] = lg;
}

__global__ __launch_bounds__(256) void zgram_logits_kernel(const float* __restrict__ zn,
                                                           float* __restrict__ out) {
  int bj = blockIdx.x, bi = blockIdx.y;
  if (bi > bj) return;                 // gram is symmetric; mirror-scatter below
  const int ib = bi * 128, jb = bj * 128;
  const float* Ab = zn + (size_t)ib * DZ;
  const float* Bb = zn + (size_t)jb * DZ;

  __shared__ __attribute__((aligned(16))) float As[16][128];
  __shared__ __attribute__((aligned(16))) float Bs[16][128];

  int tid = threadIdx.x;
  int tx = tid & 15, ty = tid >> 4;
  int lrow = tid >> 1;
  int lk = (tid & 1) * 8;

  float acc[8][8];
#pragma unroll
  for (int i = 0; i < 8; i++)
#pragma unroll
    for (int j = 0; j < 8; j++) acc[i][j] = 0.f;

  for (int k0 = 0; k0 < DZ; k0 += 16) {
    float4 a0 = *(const float4*)(Ab + (size_t)lrow * DZ + k0 + lk);
    float4 a1 = *(const float4*)(Ab + (size_t)lrow * DZ + k0 + lk + 4);
    float4 b0 = *(const float4*)(Bb + (size_t)lrow * DZ + k0 + lk);
    float4 b1 = *(const float4*)(Bb + (size_t)lrow * DZ + k0 + lk + 4);
    __syncthreads();
    As[lk + 0][lrow] = a0.x; As[lk + 1][lrow] = a0.y; As[lk + 2][lrow] = a0.z; As[lk + 3][lrow] = a0.w;
    As[lk + 4][lrow] = a1.x; As[lk + 5][lrow] = a1.y; As[lk + 6][lrow] = a1.z; As[lk + 7][lrow] = a1.w;
    Bs[lk + 0][lrow] = b0.x; Bs[lk + 1][lrow] = b0.y; Bs[lk + 2][lrow] = b0.z; Bs[lk + 3][lrow] = b0.w;
    Bs[lk + 4][lrow] = b1.x; Bs[lk + 5][lrow] = b1.y; Bs[lk + 6][lrow] = b1.z; Bs[lk + 7][lrow] = b1.w;
    __syncthreads();
#pragma unroll
    for (int kk = 0; kk < 16; kk++) {
      float4 av0 = *(const float4*)&As[kk][ty * 8];
      float4 av1 = *(const float4*)&As[kk][ty * 8 + 4];
      float4 bv0 = *(const float4*)&Bs[kk][tx * 4];
      float4 bv1 = *(const float4*)&Bs[kk][tx * 4 + 64];
      float a_[8] = {av0.x, av0.y, av0.z, av0.w, av1.x, av1.y, av1.z, av1.w};
      float b_[8] = {bv0.x, bv0.y, bv0.z, bv0.w, bv1.x, bv1.y, bv1.z, bv1.w};
#pragma unroll
      for (int v = 0; v < 8; v++)
#pragma unroll
        for (int u = 0; u < 8; u++) acc[v][u] += a_[v] * b_[u];
    }
  }

#pragma unroll
  for (int v = 0; v < 8; v++) {
    int R = ib + ty * 8 + v;
#pragma unroll
    for (int u = 0; u < 8; u++) {
      int C = jb + tx * 4 + (u & 3) + (u >> 2) * 64;
      if (C == R) continue;
      float lg = 2.f * acc[v][u];  // /TEMPERATURE(0.5)
      store_logit(out, R, C, lg);
      if (bi != bj) store_logit(out, C, R, lg);
    }
  }
}

// ---------------- labels ----------------
__global__ void labels_kernel(float* __restrict__ out) {
  int i = blockIdx.x * 256 + threadIdx.x;
  if (i < N2) out[OFF_LAB + i] = (float)(i & (B_ - 1));
}

// ---------------- per-row loss ----------------
__global__ __launch_bounds__(256) void loss_row_kernel(const float* __restrict__ out,
                                                       float* __restrict__ lossp) {
  int r = blockIdx.x, tid = threadIdx.x;
  const float* row = out + OFF_LOGITS + (size_t)r * NL;
  __shared__ __attribute__((aligned(16))) float buf[NL];
  __shared__ float red[4];
  float m = -1e30f;
  for (int j = tid; j < NL; j += 256) { float v = row[j]; buf[j] = v; m = fmaxf(m, v); }
  for (int off = 32; off; off >>= 1) m = fmaxf(m, __shfl_down(m, off, 64));
  if ((tid & 63) == 0) red[tid >> 6] = m;
  __syncthreads();
  m = fmaxf(fmaxf(red[0], red[1]), fmaxf(red[2], red[3]));
  float s = 0.f;
  for (int j = tid; j < NL; j += 256) s += expf(buf[j] - m);
  for (int off = 32; off; off >>= 1) s += __shfl_down(s, off, 64);
  __syncthreads();
  if ((tid & 63) == 0) red[tid >> 6] = s;
  __syncthreads();
  if (tid == 0) {
    float S = red[0] + red[1] + red[2] + red[3];
    lossp[r] = m + logf(S) - buf[r & (B_ - 1)];
  }
}

// ---------------- final mean ----------------
__global__ void finalize_kernel(const float* __restrict__ lossp, float* __restrict__ out) {
  int tid = threadIdx.x;
  float s = 0.f;
  for (int j = tid; j < N2; j += 256) s += lossp[j];
  for (int off = 32; off; off >>= 1) s += __shfl_down(s, off, 64);
  __shared__ float red[4];
  if ((tid & 63) == 0) red[tid >> 6] = s;
  __syncthreads();
  if (tid == 0) out[0] = (red[0] + red[1] + red[2] + red[3]) / (float)N2;
}

extern "C" void kernel_launch(void* const* d_in, const int* in_sizes, int n_in,
                              void* d_out, int out_size, void* d_ws, size_t ws_size,
                              hipStream_t stream) {
  const float* z0 = (const float*)d_in[0];
  const float* z1 = (const float*)d_in[1];
  const float* f0 = (const float*)d_in[2];
  const float* f1 = (const float*)d_in[3];
  float* out = (float*)d_out;
  float* ws = (float*)d_ws;
  float* zn = ws + WS_ZN;
  float* fn = ws + WS_FN;
  float* lp = ws + WS_LP;
  float* D2 = out;  // scratch overlay on d_out[0 .. N2*N2)

  const size_t need_bytes = ((size_t)WS_FCOMB + (size_t)N2 * DF) * sizeof(float);  // ~71.4 MB
  dim3 g(64, 64);

  if (ws_size >= need_bytes) {
    unsigned short* fcomb = (unsigned short*)(ws + WS_FCOMB);
    convert_kernel<<<N2, 256, 0, stream>>>(f0, f1, fcomb, fn);  // fuses fnorm
    znorm_kernel<<<N2, 128, 0, stream>>>(z0, z1, zn);
    d2_gemm_pre_kernel<<<g, 256, 0, stream>>>(fcomb, fn, D2);
  } else {
    fnorm_kernel<<<N2, 256, 0, stream>>>(f0, f1, fn);
    znorm_kernel<<<N2, 128, 0, stream>>>(z0, z1, zn);
    d2_gemm_mfma_kernel<<<g, 256, 0, stream>>>(f0, f1, fn, D2);
  }

  select_lid_kernel<<<N2, 256, 0, stream>>>(D2, out);       // lids -> final slots (past D2)
  zgram_logits_kernel<<<g, 256, 0, stream>>>(zn, out);      // overwrites D2 scratch with logits
  labels_kernel<<<(N2 + 255) / 256, 256, 0, stream>>>(out);
  loss_row_kernel<<<N2, 256, 0, stream>>>(out, lp);
  finalize_kernel<<<1, 256, 0, stream>>>(lp, out);
}

// Round 3
// 1247.686 us; speedup vs baseline: 1.1636x; 1.1636x over previous
//
#include <hip/hip_runtime.h>
#include <math.h>

#define B_   4096
#define DZ   128
#define DF   2048
#define N2   8192            // 2*B_
#define NL   8191            // 2*B_ - 1

// d_out layout (floats): [loss(1)][logits(8192*8191)][labels(8192)][lids32(8192)][lids512(8192)]
#define OFF_LOGITS 1
#define OFF_LAB  (1 + (size_t)N2 * NL)      // 67100673
#define OFF_L32  (OFF_LAB + N2)             // 67108865
#define OFF_L512 (OFF_L32 + N2)             // 67117057
// D2 scratch overlays d_out[0 .. N2*N2) = [0, 67108864) — disjoint from lids slots.

// ws layout (floats)
#define WS_ZN 0
#define WS_FN ((size_t)N2 * DZ)             // 1048576
#define WS_LP (WS_FN + N2)
#define WS_FCOMB (WS_LP + N2)               // bf16 hi/lo precomp: N2*DF floats (= N2*DF*2 shorts)

typedef __attribute__((ext_vector_type(8))) __bf16 bf16x8;
typedef __attribute__((ext_vector_type(8))) unsigned short ushort8;
typedef __attribute__((ext_vector_type(4))) float f32x4;

// round-to-nearest-even fp32 -> bf16 bits (inputs are finite Gaussians; no NaN path needed)
__device__ __forceinline__ unsigned short f2bf(float f) {
  unsigned u = __float_as_uint(f);
  return (unsigned short)((u + 0x7FFFu + ((u >> 16) & 1u)) >> 16);
}
__device__ __forceinline__ float bf2f(unsigned short h) {
  return __uint_as_float(((unsigned)h) << 16);
}

// ---------------- row norms of f (||f_i||^2) — fallback path only ----------------
__global__ __launch_bounds__(256) void fnorm_kernel(const float* __restrict__ f0,
                                                    const float* __restrict__ f1,
                                                    float* __restrict__ fn) {
  int r = blockIdx.x;
  const float* row = (r < B_) ? f0 + (size_t)r * DF : f1 + (size_t)(r - B_) * DF;
  float s = 0.f;
  for (int j = threadIdx.x; j < DF; j += 256) { float v = row[j]; s += v * v; }
  for (int off = 32; off; off >>= 1) s += __shfl_down(s, off, 64);
  __shared__ float red[4];
  if ((threadIdx.x & 63) == 0) red[threadIdx.x >> 6] = s;
  __syncthreads();
  if (threadIdx.x == 0) fn[r] = red[0] + red[1] + red[2] + red[3];
}

// ---------------- fused: fp32 -> bf16 hi/lo precompute + row norms ----------------
// fcomb layout per row r: 64 slabs x 128 B; slab s = [hi(32 shorts) | lo(32 shorts)]
// covering k = s*32 .. s*32+32. Row byte stride = 8192.
__global__ __launch_bounds__(256) void convert_kernel(const float* __restrict__ f0,
                                                      const float* __restrict__ f1,
                                                      unsigned short* __restrict__ fcomb,
                                                      float* __restrict__ fn) {
  int r = blockIdx.x, t = threadIdx.x;
  const float* row = (r < B_) ? f0 + (size_t)r * DF : f1 + (size_t)(r - B_) * DF;
  float4 v0 = *(const float4*)(row + t * 8);
  float4 v1 = *(const float4*)(row + t * 8 + 4);
  float v[8] = {v0.x, v0.y, v0.z, v0.w, v1.x, v1.y, v1.z, v1.w};
  ushort8 h, l;
  float s = 0.f;
#pragma unroll
  for (int j = 0; j < 8; j++) {
    unsigned short hb = f2bf(v[j]);
    h[j] = hb;
    l[j] = f2bf(v[j] - bf2f(hb));
    s += v[j] * v[j];
  }
  unsigned short* rowp = fcomb + (size_t)r * (2 * DF);
  int slab = t >> 2, c = t & 3;           // thread covers hi chunk c, lo chunk 4+c of slab
  *(ushort8*)(rowp + slab * 64 + c * 8) = h;
  *(ushort8*)(rowp + slab * 64 + 32 + c * 8) = l;
  for (int off = 32; off; off >>= 1) s += __shfl_down(s, off, 64);
  __shared__ float red[4];
  if ((t & 63) == 0) red[t >> 6] = s;
  __syncthreads();
  if (t == 0) fn[r] = red[0] + red[1] + red[2] + red[3];
}

// ---------------- normalize z rows ----------------
__global__ void znorm_kernel(const float* __restrict__ z0, const float* __restrict__ z1,
                             float* __restrict__ zn) {
  int r = blockIdx.x, t = threadIdx.x;  // 128 threads
  const float* row = (r < B_) ? z0 + (size_t)r * DZ : z1 + (size_t)(r - B_) * DZ;
  float v = row[t];
  float s = v * v;
  for (int off = 32; off; off >>= 1) s += __shfl_down(s, off, 64);
  __shared__ float red[2];
  if ((t & 63) == 0) red[t >> 6] = s;
  __syncthreads();
  float n = sqrtf(red[0] + red[1]);
  zn[(size_t)r * DZ + t] = v / fmaxf(n, 1e-12f);
}

// ---------------- D2 GEMM, precomputed bf16 hi/lo, 2-phase pipelined (T3 minimum recipe) ----------------
// 128x128 tile, 4 waves (2x2 quadrants of 4x4 16x16 MFMA tiles), 3 passes (hh+hl+lh).
// LDS: 2 buffers x (A[128][64s] ++ B[128][64s]) = 64 KB. Per slab: issue next-slab
// global_load_lds FIRST, then ds_read+MFMA current, then ONE vmcnt(0)+s_barrier —
// prefetch latency hides under ~1000cy of compute instead of being drained every slab
// by __syncthreads()'s forced vmcnt(0) before compute (the measured 37%-MfmaUtil stall).
// Swizzle (rule 21, both-sides): 16B-chunk x at row r holds data chunk x^(r&7);
// applied on the per-lane GLOBAL source address at stage time and on the ds_read address.
__global__ __launch_bounds__(256) void d2_gemm_pre_kernel(const unsigned short* __restrict__ fcomb,
                                                          const float* __restrict__ fn,
                                                          float* __restrict__ D2) {
  int bj = blockIdx.x, bi = blockIdx.y;
  if (bi > bj) return;
  const int ib = bi * 128, jb = bj * 128;

  __shared__ __attribute__((aligned(16))) unsigned short TILE[2][2 * 128 * 64];

  const int tid = threadIdx.x;
  const int lane = tid & 63;
  const int wave = tid >> 6;
  const int wr = (wave >> 1) * 64;     // quadrant row base within tile
  const int wc = (wave & 1) * 64;      // quadrant col base within tile
  const int m  = lane & 15;            // frag row/col within 16
  const int kg = lane >> 4;            // k-group (0..3) -> k = kg*8 + j

  // staging: wave w covers LDS bytes [w*8192, (w+1)*8192): w0/w1 = A rows 0-63/64-127, w2/w3 = B.
  const int lrow8 = lane >> 3;                 // 0..7: row within 8-row stripe
  const int lchk  = (lane & 7) ^ lrow8;        // inverse-swizzled source chunk
  const int grow0 = ((wave < 2) ? ib : jb) + (wave & 1) * 64;
  const char* gsrc = (const char*)fcomb + (size_t)(grow0 + lrow8) * 8192 + (size_t)lchk * 16;

  f32x4 acc[4][4];
#pragma unroll
  for (int i = 0; i < 4; i++)
#pragma unroll
    for (int j = 0; j < 4; j++) acc[i][j] = (f32x4)0.f;

  // prologue: stage slab 0 into TILE[0]
  {
    char* lds0 = (char*)&TILE[0][0] + wave * 8192;
#pragma unroll
    for (int i = 0; i < 8; i++)
      __builtin_amdgcn_global_load_lds(
          (const __attribute__((address_space(1))) void*)(gsrc + (size_t)i * 65536),
          (__attribute__((address_space(3))) void*)(lds0 + i * 1024), 16, 0, 0);
    gsrc += 128;
  }
  asm volatile("s_waitcnt vmcnt(0)" ::: "memory");
  __builtin_amdgcn_s_barrier();
  __builtin_amdgcn_sched_barrier(0);

  for (int s = 0; s < 64; ++s) {
    const int cur = s & 1;
    if (s < 63) {
      char* ldsn = (char*)&TILE[cur ^ 1][0] + wave * 8192;
#pragma unroll
      for (int i = 0; i < 8; i++)
        __builtin_amdgcn_global_load_lds(
            (const __attribute__((address_space(1))) void*)(gsrc + (size_t)i * 65536),
            (__attribute__((address_space(3))) void*)(ldsn + i * 1024), 16, 0, 0);
      gsrc += 128;
    }

    const unsigned short* T = &TILE[cur][0];
    bf16x8 a_h[4], a_l[4], b_h[4], b_l[4];
#pragma unroll
    for (int t4 = 0; t4 < 4; t4++) {
      int ra = wr + t4 * 16 + m;
      int rb = wc + t4 * 16 + m;
      int sa = ra & 7, sb = rb & 7;
      a_h[t4] = *(const bf16x8*)&T[ra * 64 + ((kg ^ sa) << 3)];
      a_l[t4] = *(const bf16x8*)&T[ra * 64 + (((kg | 4) ^ sa) << 3)];
      b_h[t4] = *(const bf16x8*)&T[8192 + rb * 64 + ((kg ^ sb) << 3)];
      b_l[t4] = *(const bf16x8*)&T[8192 + rb * 64 + (((kg | 4) ^ sb) << 3)];
    }
#pragma unroll
    for (int ti = 0; ti < 4; ti++)
#pragma unroll
      for (int tj = 0; tj < 4; tj++) {
        acc[ti][tj] = __builtin_amdgcn_mfma_f32_16x16x32_bf16(a_h[ti], b_h[tj], acc[ti][tj], 0, 0, 0);
        acc[ti][tj] = __builtin_amdgcn_mfma_f32_16x16x32_bf16(a_h[ti], b_l[tj], acc[ti][tj], 0, 0, 0);
        acc[ti][tj] = __builtin_amdgcn_mfma_f32_16x16x32_bf16(a_l[ti], b_h[tj], acc[ti][tj], 0, 0, 0);
      }

    // wait only for THIS wave's prefetch (had the whole compute phase to land), then sync
    asm volatile("s_waitcnt vmcnt(0)" ::: "memory");
    __builtin_amdgcn_s_barrier();
    __builtin_amdgcn_sched_barrier(0);
  }

  // epilogue: D2[i][j] = max(fn[i]+fn[j]-2*dot, 0); direct + mirror stores
  // C/D layout: col = lane&15, row = (lane>>4)*4 + reg
#pragma unroll
  for (int ti = 0; ti < 4; ti++) {
    int irow0 = ib + wr + ti * 16 + kg * 4;
    float4 fni = *(const float4*)&fn[irow0];
    float fniv[4] = {fni.x, fni.y, fni.z, fni.w};
#pragma unroll
    for (int tj = 0; tj < 4; tj++) {
      int jg = jb + wc + tj * 16 + m;
      float fnj = fn[jg];
      float val[4];
#pragma unroll
      for (int r = 0; r < 4; r++)
        val[r] = fmaxf(fniv[r] + fnj - 2.f * acc[ti][tj][r], 0.f);
#pragma unroll
      for (int r = 0; r < 4; r++)
        D2[(size_t)(irow0 + r) * N2 + jg] = val[r];
      if (bi != bj)
        *(float4*)&D2[(size_t)jg * N2 + irow0] = make_float4(val[0], val[1], val[2], val[3]);
    }
  }
}

// ---------------- D2 via bf16 hi/lo split MFMA (fallback if ws too small) ----------------
#define LSTR 40   // padded LDS row stride in shorts (80 B)
__global__ __launch_bounds__(256) void d2_gemm_mfma_kernel(const float* __restrict__ f0,
                                                           const float* __restrict__ f1,
                                                           const float* __restrict__ fn,
                                                           float* __restrict__ D2) {
  int bj = blockIdx.x, bi = blockIdx.y;
  if (bi > bj) return;
  const int ib = bi * 128, jb = bj * 128;
  const float* Ab = (ib < B_) ? f0 + (size_t)ib * DF : f1 + (size_t)(ib - B_) * DF;
  const float* Bb = (jb < B_) ? f0 + (size_t)jb * DF : f1 + (size_t)(jb - B_) * DF;

  __shared__ __attribute__((aligned(16))) unsigned short Ah[128 * LSTR];
  __shared__ __attribute__((aligned(16))) unsigned short Al[128 * LSTR];
  __shared__ __attribute__((aligned(16))) unsigned short Bh[128 * LSTR];
  __shared__ __attribute__((aligned(16))) unsigned short Bl[128 * LSTR];

  const int tid = threadIdx.x;
  const int lane = tid & 63;
  const int wave = tid >> 6;
  const int wr = (wave >> 1) * 64;
  const int wc = (wave & 1) * 64;
  const int m  = lane & 15;
  const int kg = lane >> 4;

  const int lrow = tid >> 1;
  const int lhalf = tid & 1;
  const float* arow = Ab + (size_t)lrow * DF + lhalf * 16;
  const float* brow = Bb + (size_t)lrow * DF + lhalf * 16;
  const int wbase = lrow * LSTR + lhalf * 16;

  f32x4 acc[4][4];
#pragma unroll
  for (int i = 0; i < 4; i++)
#pragma unroll
    for (int j = 0; j < 4; j++) acc[i][j] = (f32x4)0.f;

  for (int k0 = 0; k0 < DF; k0 += 32) {
    float av[16], bv[16];
#pragma unroll
    for (int q = 0; q < 4; q++) {
      float4 t = *(const float4*)(arow + k0 + q * 4);
      av[q * 4 + 0] = t.x; av[q * 4 + 1] = t.y; av[q * 4 + 2] = t.z; av[q * 4 + 3] = t.w;
    }
#pragma unroll
    for (int q = 0; q < 4; q++) {
      float4 t = *(const float4*)(brow + k0 + q * 4);
      bv[q * 4 + 0] = t.x; bv[q * 4 + 1] = t.y; bv[q * 4 + 2] = t.z; bv[q * 4 + 3] = t.w;
    }

    __syncthreads();

    ushort8 ah0, ah1, al0, al1, bh0, bh1, bl0, bl1;
#pragma unroll
    for (int j = 0; j < 8; j++) {
      unsigned short h = f2bf(av[j]);     ah0[j] = h; al0[j] = f2bf(av[j] - bf2f(h));
      unsigned short h2 = f2bf(av[j + 8]); ah1[j] = h2; al1[j] = f2bf(av[j + 8] - bf2f(h2));
      unsigned short h3 = f2bf(bv[j]);     bh0[j] = h3; bl0[j] = f2bf(bv[j] - bf2f(h3));
      unsigned short h4 = f2bf(bv[j + 8]); bh1[j] = h4; bl1[j] = f2bf(bv[j + 8] - bf2f(h4));
    }
    *(ushort8*)&Ah[wbase] = ah0;     *(ushort8*)&Ah[wbase + 8] = ah1;
    *(ushort8*)&Al[wbase] = al0;     *(ushort8*)&Al[wbase + 8] = al1;
    *(ushort8*)&Bh[wbase] = bh0;     *(ushort8*)&Bh[wbase + 8] = bh1;
    *(ushort8*)&Bl[wbase] = bl0;     *(ushort8*)&Bl[wbase + 8] = bl1;

    __syncthreads();

    bf16x8 a_h[4], a_l[4], b_h[4], b_l[4];
#pragma unroll
    for (int t4 = 0; t4 < 4; t4++) {
      int aoff = (wr + t4 * 16 + m) * LSTR + kg * 8;
      int boff = (wc + t4 * 16 + m) * LSTR + kg * 8;
      a_h[t4] = *(const bf16x8*)&Ah[aoff];
      a_l[t4] = *(const bf16x8*)&Al[aoff];
      b_h[t4] = *(const bf16x8*)&Bh[boff];
      b_l[t4] = *(const bf16x8*)&Bl[boff];
    }
#pragma unroll
    for (int ti = 0; ti < 4; ti++)
#pragma unroll
      for (int tj = 0; tj < 4; tj++) {
        acc[ti][tj] = __builtin_amdgcn_mfma_f32_16x16x32_bf16(a_h[ti], b_h[tj], acc[ti][tj], 0, 0, 0);
        acc[ti][tj] = __builtin_amdgcn_mfma_f32_16x16x32_bf16(a_h[ti], b_l[tj], acc[ti][tj], 0, 0, 0);
        acc[ti][tj] = __builtin_amdgcn_mfma_f32_16x16x32_bf16(a_l[ti], b_h[tj], acc[ti][tj], 0, 0, 0);
      }
  }

#pragma unroll
  for (int ti = 0; ti < 4; ti++) {
    int irow0 = ib + wr + ti * 16 + kg * 4;
    float4 fni = *(const float4*)&fn[irow0];
    float fniv[4] = {fni.x, fni.y, fni.z, fni.w};
#pragma unroll
    for (int tj = 0; tj < 4; tj++) {
      int jg = jb + wc + tj * 16 + m;
      float fnj = fn[jg];
      float val[4];
#pragma unroll
      for (int r = 0; r < 4; r++)
        val[r] = fmaxf(fniv[r] + fnj - 2.f * acc[ti][tj][r], 0.f);
#pragma unroll
      for (int r = 0; r < 4; r++)
        D2[(size_t)(irow0 + r) * N2 + jg] = val[r];
      if (bi != bj)
        *(float4*)&D2[(size_t)jg * N2 + irow0] = make_float4(val[0], val[1], val[2], val[3]);
    }
  }
}

// ---------------- per-row 513-smallest + LID (R1-verified version) ----------------
__global__ __launch_bounds__(256) void select_lid_kernel(const float* __restrict__ D2,
                                                         float* __restrict__ out) {
  int r = blockIdx.x, tid = threadIdx.x;
  const float* row = D2 + (size_t)r * N2;
  unsigned key[32];
#pragma unroll
  for (int j = 0; j < 32; j++) {
    float v = fmaxf(row[tid + j * 256], 0.f);   // clip(d2, 0); nonneg floats: bits are order-preserving
    key[j] = __float_as_uint(v);
  }
  __shared__ int wcnt[32][4];
  __shared__ int pref[256];
  __shared__ unsigned cand[512];
  __shared__ float rr[8];

  // bit-descent: T = max{x : count(key < x) <= 512} = 513th smallest key
  unsigned T = 0;
  for (int b = 30; b >= 0; b--) {
    unsigned t = T | (1u << b);
    int c = 0;
#pragma unroll
    for (int j = 0; j < 32; j++) c += (key[j] < t) ? 1 : 0;
    for (int off = 32; off; off >>= 1) c += __shfl_down(c, off, 64);
    if ((tid & 63) == 0) wcnt[b][tid >> 6] = c;
    __syncthreads();
    int tot = wcnt[b][0] + wcnt[b][1] + wcnt[b][2] + wcnt[b][3];
    if (tot <= 512) T = t;
  }

  // gather strictly-less-than-T candidates (count c0 <= 512)
  int n_t = 0;
#pragma unroll
  for (int j = 0; j < 32; j++) n_t += (key[j] < T) ? 1 : 0;
  pref[tid] = n_t;
  __syncthreads();
  for (int s = 1; s < 256; s <<= 1) {
    int v = (tid >= s) ? pref[tid - s] : 0;
    __syncthreads();
    pref[tid] += v;
    __syncthreads();
  }
  int c0 = pref[255];
  int base = pref[tid] - n_t;
  cand[tid] = 0xFFFFFFFFu;
  cand[tid + 256] = 0xFFFFFFFFu;
  __syncthreads();
  {
    int idx = base;
#pragma unroll
    for (int j = 0; j < 32; j++)
      if (key[j] < T) cand[idx++] = key[j];
  }
  __syncthreads();

  // bitonic sort 512 ascending
  for (int k = 2; k <= 512; k <<= 1) {
    for (int j = k >> 1; j > 0; j >>= 1) {
      int i = ((tid & ~(j - 1)) << 1) | (tid & (j - 1));
      int p = i | j;
      bool up = (i & k) == 0;
      unsigned a = cand[i], b2 = cand[p];
      if ((a > b2) == up) { cand[i] = b2; cand[p] = a; }
      __syncthreads();
    }
  }

  // sorted 513-ascending = cand[0..c0) ++ (513-c0) copies of T; element 0 is the self (dropped)
  float d32  = sqrtf(__uint_as_float(32  < c0 ? cand[32]  : T));
  float d512 = sqrtf(__uint_as_float(512 < c0 ? cand[512] : T));
  int i1 = tid + 1, i2 = tid + 257;
  float di1 = sqrtf(__uint_as_float(i1 < c0 ? cand[i1] : T));
  float di2 = sqrtf(__uint_as_float(i2 < c0 ? cand[i2] : T));
  float s32 = (i1 <= 32) ? logf(di1 / d32 + 1e-12f) : 0.f;
  float s512 = logf(di1 / d512 + 1e-12f) + logf(di2 / d512 + 1e-12f);
  for (int off = 32; off; off >>= 1) {
    s32 += __shfl_down(s32, off, 64);
    s512 += __shfl_down(s512, off, 64);
  }
  if ((tid & 63) == 0) { rr[tid >> 6] = s32; rr[4 + (tid >> 6)] = s512; }
  __syncthreads();
  if (tid == 0) {
    float S32 = rr[0] + rr[1] + rr[2] + rr[3];
    float S512 = rr[4] + rr[5] + rr[6] + rr[7];
    out[OFF_L32 + r] = -32.f / S32;
    out[OFF_L512 + r] = -512.f / S512;
  }
}

// ---------------- logits = reshuffled z-gram / T (R1-verified full-grid version) ----------------
__global__ __launch_bounds__(256) void zgram_logits_kernel(const float* __restrict__ zn,
                                                           float* __restrict__ out) {
  int bj = blockIdx.x, bi = blockIdx.y;
  const int ib = bi * 128, jb = bj * 128;
  const float* Ab = zn + (size_t)ib * DZ;
  const float* Bb = zn + (size_t)jb * DZ;

  __shared__ __attribute__((aligned(16))) float As[16][128];
  __shared__ __attribute__((aligned(16))) float Bs[16][128];

  int tid = threadIdx.x;
  int tx = tid & 15, ty = tid >> 4;
  int lrow = tid >> 1;
  int lk = (tid & 1) * 8;

  float acc[8][8];
#pragma unroll
  for (int i = 0; i < 8; i++)
#pragma unroll
    for (int j = 0; j < 8; j++) acc[i][j] = 0.f;

  for (int k0 = 0; k0 < DZ; k0 += 16) {
    float4 a0 = *(const float4*)(Ab + (size_t)lrow * DZ + k0 + lk);
    float4 a1 = *(const float4*)(Ab + (size_t)lrow * DZ + k0 + lk + 4);
    float4 b0 = *(const float4*)(Bb + (size_t)lrow * DZ + k0 + lk);
    float4 b1 = *(const float4*)(Bb + (size_t)lrow * DZ + k0 + lk + 4);
    __syncthreads();
    As[lk + 0][lrow] = a0.x; As[lk + 1][lrow] = a0.y; As[lk + 2][lrow] = a0.z; As[lk + 3][lrow] = a0.w;
    As[lk + 4][lrow] = a1.x; As[lk + 5][lrow] = a1.y; As[lk + 6][lrow] = a1.z; As[lk + 7][lrow] = a1.w;
    Bs[lk + 0][lrow] = b0.x; Bs[lk + 1][lrow] = b0.y; Bs[lk + 2][lrow] = b0.z; Bs[lk + 3][lrow] = b0.w;
    Bs[lk + 4][lrow] = b1.x; Bs[lk + 5][lrow] = b1.y; Bs[lk + 6][lrow] = b1.z; Bs[lk + 7][lrow] = b1.w;
    __syncthreads();
#pragma unroll
    for (int kk = 0; kk < 16; kk++) {
      float4 av0 = *(const float4*)&As[kk][ty * 8];
      float4 av1 = *(const float4*)&As[kk][ty * 8 + 4];
      float4 bv0 = *(const float4*)&Bs[kk][tx * 4];
      float4 bv1 = *(const float4*)&Bs[kk][tx * 4 + 64];
      float a_[8] = {av0.x, av0.y, av0.z, av0.w, av1.x, av1.y, av1.z, av1.w};
      float b_[8] = {bv0.x, bv0.y, bv0.z, bv0.w, bv1.x, bv1.y, bv1.z, bv1.w};
#pragma unroll
      for (int v = 0; v < 8; v++)
#pragma unroll
        for (int u = 0; u < 8; u++) acc[v][u] += a_[v] * b_[u];
    }
  }

#pragma unroll
  for (int v = 0; v < 8; v++) {
    int rrow = ib + ty * 8 + v;
#pragma unroll
    for (int u = 0; u < 8; u++) {
      int c = jb + tx * 4 + (u & 3) + (u >> 2) * 64;
      if (c == rrow) continue;
      float lg = 2.f * acc[v][u];  // /TEMPERATURE(0.5)
      int col;
      if (rrow < B_) col = (c >= B_) ? (c - B_) : (B_ + c - (c > rrow ? 1 : 0));
      else           col = (c < B_) ? c : (c - (c > rrow ? 1 : 0));
      out[OFF_LOGITS + (size_t)rrow * NL + col] = lg;
    }
  }
}

// ---------------- labels ----------------
__global__ void labels_kernel(float* __restrict__ out) {
  int i = blockIdx.x * 256 + threadIdx.x;
  if (i < N2) out[OFF_LAB + i] = (float)(i & (B_ - 1));
}

// ---------------- per-row loss ----------------
__global__ __launch_bounds__(256) void loss_row_kernel(const float* __restrict__ out,
                                                       float* __restrict__ lossp) {
  int r = blockIdx.x, tid = threadIdx.x;
  const float* row = out + OFF_LOGITS + (size_t)r * NL;
  __shared__ __attribute__((aligned(16))) float buf[NL];
  __shared__ float red[4];
  float m = -1e30f;
  for (int j = tid; j < NL; j += 256) { float v = row[j]; buf[j] = v; m = fmaxf(m, v); }
  for (int off = 32; off; off >>= 1) m = fmaxf(m, __shfl_down(m, off, 64));
  if ((tid & 63) == 0) red[tid >> 6] = m;
  __syncthreads();
  m = fmaxf(fmaxf(red[0], red[1]), fmaxf(red[2], red[3]));
  float s = 0.f;
  for (int j = tid; j < NL; j += 256) s += expf(buf[j] - m);
  for (int off = 32; off; off >>= 1) s += __shfl_down(s, off, 64);
  __syncthreads();
  if ((tid & 63) == 0) red[tid >> 6] = s;
  __syncthreads();
  if (tid == 0) {
    float S = red[0] + red[1] + red[2] + red[3];
    lossp[r] = m + logf(S) - buf[r & (B_ - 1)];
  }
}

// ---------------- final mean ----------------
__global__ void finalize_kernel(const float* __restrict__ lossp, float* __restrict__ out) {
  int tid = threadIdx.x;
  float s = 0.f;
  for (int j = tid; j < N2; j += 256) s += lossp[j];
  for (int off = 32; off; off >>= 1) s += __shfl_down(s, off, 64);
  __shared__ float red[4];
  if ((tid & 63) == 0) red[tid >> 6] = s;
  __syncthreads();
  if (tid == 0) out[0] = (red[0] + red[1] + red[2] + red[3]) / (float)N2;
}

extern "C" void kernel_launch(void* const* d_in, const int* in_sizes, int n_in,
                              void* d_out, int out_size, void* d_ws, size_t ws_size,
                              hipStream_t stream) {
  const float* z0 = (const float*)d_in[0];
  const float* z1 = (const float*)d_in[1];
  const float* f0 = (const float*)d_in[2];
  const float* f1 = (const float*)d_in[3];
  float* out = (float*)d_out;
  float* ws = (float*)d_ws;
  float* zn = ws + WS_ZN;
  float* fn = ws + WS_FN;
  float* lp = ws + WS_LP;
  float* D2 = out;  // scratch overlay on d_out[0 .. N2*N2)

  const size_t need_bytes = ((size_t)WS_FCOMB + (size_t)N2 * DF) * sizeof(float);  // ~71.4 MB
  dim3 g(64, 64);

  if (ws_size >= need_bytes) {
    unsigned short* fcomb = (unsigned short*)(ws + WS_FCOMB);
    convert_kernel<<<N2, 256, 0, stream>>>(f0, f1, fcomb, fn);  // fuses fnorm
    znorm_kernel<<<N2, 128, 0, stream>>>(z0, z1, zn);
    d2_gemm_pre_kernel<<<g, 256, 0, stream>>>(fcomb, fn, D2);
  } else {
    fnorm_kernel<<<N2, 256, 0, stream>>>(f0, f1, fn);
    znorm_kernel<<<N2, 128, 0, stream>>>(z0, z1, zn);
    d2_gemm_mfma_kernel<<<g, 256, 0, stream>>>(f0, f1, fn, D2);
  }

  select_lid_kernel<<<N2, 256, 0, stream>>>(D2, out);       // lids -> final slots (past D2)
  zgram_logits_kernel<<<g, 256, 0, stream>>>(zn, out);      // overwrites D2 scratch with logits
  labels_kernel<<<(N2 + 255) / 256, 256, 0, stream>>>(out);
  loss_row_kernel<<<N2, 256, 0, stream>>>(out, lp);
  finalize_kernel<<<1, 256, 0, stream>>>(lp, out);
}

// Round 4
// 1128.197 us; speedup vs baseline: 1.2869x; 1.1059x over previous
//
#include <hip/hip_runtime.h>
#include <math.h>

#define B_   4096
#define DZ   128
#define DF   2048
#define N2   8192            // 2*B_
#define NL   8191            // 2*B_ - 1

// d_out layout (floats): [loss(1)][logits(8192*8191)][labels(8192)][lids32(8192)][lids512(8192)]
#define OFF_LOGITS 1
#define OFF_LAB  (1 + (size_t)N2 * NL)      // 67100673
#define OFF_L32  (OFF_LAB + N2)             // 67108865
#define OFF_L512 (OFF_L32 + N2)             // 67117057
// D2 scratch overlays d_out[0 .. N2*N2) = [0, 67108864) — disjoint from lids slots.

// ws layout (floats)
#define WS_ZN 0
#define WS_FN ((size_t)N2 * DZ)             // 1048576
#define WS_LP (WS_FN + N2)
#define WS_FCOMB (WS_LP + N2)               // bf16 hi/lo precomp: N2*DF floats (= N2*DF*2 shorts)
#define WS_ZCOMB (WS_FCOMB + (size_t)N2 * DF)  // z bf16 hi/lo: N2*128 floats (= N2*256 shorts)

typedef __attribute__((ext_vector_type(8))) __bf16 bf16x8;
typedef __attribute__((ext_vector_type(8))) unsigned short ushort8;
typedef __attribute__((ext_vector_type(4))) float f32x4;

// round-to-nearest-even fp32 -> bf16 bits (inputs are finite Gaussians; no NaN path needed)
__device__ __forceinline__ unsigned short f2bf(float f) {
  unsigned u = __float_as_uint(f);
  return (unsigned short)((u + 0x7FFFu + ((u >> 16) & 1u)) >> 16);
}
__device__ __forceinline__ float bf2f(unsigned short h) {
  return __uint_as_float(((unsigned)h) << 16);
}

// ---------------- row norms of f (||f_i||^2) — fallback path only ----------------
__global__ __launch_bounds__(256) void fnorm_kernel(const float* __restrict__ f0,
                                                    const float* __restrict__ f1,
                                                    float* __restrict__ fn) {
  int r = blockIdx.x;
  const float* row = (r < B_) ? f0 + (size_t)r * DF : f1 + (size_t)(r - B_) * DF;
  float s = 0.f;
  for (int j = threadIdx.x; j < DF; j += 256) { float v = row[j]; s += v * v; }
  for (int off = 32; off; off >>= 1) s += __shfl_down(s, off, 64);
  __shared__ float red[4];
  if ((threadIdx.x & 63) == 0) red[threadIdx.x >> 6] = s;
  __syncthreads();
  if (threadIdx.x == 0) fn[r] = red[0] + red[1] + red[2] + red[3];
}

// ---------------- fused: fp32 -> bf16 hi/lo precompute + row norms ----------------
// fcomb layout per row r: 64 slabs x 128 B; slab s = [hi(32 shorts) | lo(32 shorts)]
// covering k = s*32 .. s*32+32. Row byte stride = 8192.
__global__ __launch_bounds__(256) void convert_kernel(const float* __restrict__ f0,
                                                      const float* __restrict__ f1,
                                                      unsigned short* __restrict__ fcomb,
                                                      float* __restrict__ fn) {
  int r = blockIdx.x, t = threadIdx.x;
  const float* row = (r < B_) ? f0 + (size_t)r * DF : f1 + (size_t)(r - B_) * DF;
  float4 v0 = *(const float4*)(row + t * 8);
  float4 v1 = *(const float4*)(row + t * 8 + 4);
  float v[8] = {v0.x, v0.y, v0.z, v0.w, v1.x, v1.y, v1.z, v1.w};
  ushort8 h, l;
  float s = 0.f;
#pragma unroll
  for (int j = 0; j < 8; j++) {
    unsigned short hb = f2bf(v[j]);
    h[j] = hb;
    l[j] = f2bf(v[j] - bf2f(hb));
    s += v[j] * v[j];
  }
  unsigned short* rowp = fcomb + (size_t)r * (2 * DF);
  int slab = t >> 2, c = t & 3;           // thread covers hi chunk c, lo chunk 4+c of slab
  *(ushort8*)(rowp + slab * 64 + c * 8) = h;
  *(ushort8*)(rowp + slab * 64 + 32 + c * 8) = l;
  for (int off = 32; off; off >>= 1) s += __shfl_down(s, off, 64);
  __shared__ float red[4];
  if ((t & 63) == 0) red[t >> 6] = s;
  __syncthreads();
  if (t == 0) fn[r] = red[0] + red[1] + red[2] + red[3];
}

// ---------------- normalize z rows (fp32 out) — fallback path only ----------------
__global__ void znorm_kernel(const float* __restrict__ z0, const float* __restrict__ z1,
                             float* __restrict__ zn) {
  int r = blockIdx.x, t = threadIdx.x;  // 128 threads
  const float* row = (r < B_) ? z0 + (size_t)r * DZ : z1 + (size_t)(r - B_) * DZ;
  float v = row[t];
  float s = v * v;
  for (int off = 32; off; off >>= 1) s += __shfl_down(s, off, 64);
  __shared__ float red[2];
  if ((t & 63) == 0) red[t >> 6] = s;
  __syncthreads();
  float n = sqrtf(red[0] + red[1]);
  zn[(size_t)r * DZ + t] = v / fmaxf(n, 1e-12f);
}

// ---------------- normalize z rows -> bf16 hi/lo slabs (main path) ----------------
// zcomb layout per row r: 4 slabs x 128 B; slab s = [hi(32 shorts) | lo(32 shorts)]
// covering k = s*32 .. s*32+32. Row byte stride = 512.
__global__ void znorm2_kernel(const float* __restrict__ z0, const float* __restrict__ z1,
                              unsigned short* __restrict__ zcomb) {
  int r = blockIdx.x, t = threadIdx.x;  // 128 threads
  const float* row = (r < B_) ? z0 + (size_t)r * DZ : z1 + (size_t)(r - B_) * DZ;
  float v = row[t];
  float s = v * v;
  for (int off = 32; off; off >>= 1) s += __shfl_down(s, off, 64);
  __shared__ float red[2];
  if ((t & 63) == 0) red[t >> 6] = s;
  __syncthreads();
  float n = sqrtf(red[0] + red[1]);
  float vn = v / fmaxf(n, 1e-12f);
  unsigned short hb = f2bf(vn);
  unsigned short lb = f2bf(vn - bf2f(hb));
  unsigned short* rowp = zcomb + (size_t)r * 256;
  int slab = t >> 5, p = t & 31;
  rowp[slab * 64 + p] = hb;
  rowp[slab * 64 + 32 + p] = lb;
}

// ---------------- D2 GEMM, precomputed bf16 hi/lo, 2-phase pipelined (R3-verified) ----------------
__global__ __launch_bounds__(256) void d2_gemm_pre_kernel(const unsigned short* __restrict__ fcomb,
                                                          const float* __restrict__ fn,
                                                          float* __restrict__ D2) {
  int bj = blockIdx.x, bi = blockIdx.y;
  if (bi > bj) return;
  const int ib = bi * 128, jb = bj * 128;

  __shared__ __attribute__((aligned(16))) unsigned short TILE[2][2 * 128 * 64];

  const int tid = threadIdx.x;
  const int lane = tid & 63;
  const int wave = tid >> 6;
  const int wr = (wave >> 1) * 64;     // quadrant row base within tile
  const int wc = (wave & 1) * 64;      // quadrant col base within tile
  const int m  = lane & 15;            // frag row/col within 16
  const int kg = lane >> 4;            // k-group (0..3) -> k = kg*8 + j

  // staging: wave w covers LDS bytes [w*8192, (w+1)*8192): w0/w1 = A rows 0-63/64-127, w2/w3 = B.
  const int lrow8 = lane >> 3;                 // 0..7: row within 8-row stripe
  const int lchk  = (lane & 7) ^ lrow8;        // inverse-swizzled source chunk
  const int grow0 = ((wave < 2) ? ib : jb) + (wave & 1) * 64;
  const char* gsrc = (const char*)fcomb + (size_t)(grow0 + lrow8) * 8192 + (size_t)lchk * 16;

  f32x4 acc[4][4];
#pragma unroll
  for (int i = 0; i < 4; i++)
#pragma unroll
    for (int j = 0; j < 4; j++) acc[i][j] = (f32x4)0.f;

  // prologue: stage slab 0 into TILE[0]
  {
    char* lds0 = (char*)&TILE[0][0] + wave * 8192;
#pragma unroll
    for (int i = 0; i < 8; i++)
      __builtin_amdgcn_global_load_lds(
          (const __attribute__((address_space(1))) void*)(gsrc + (size_t)i * 65536),
          (__attribute__((address_space(3))) void*)(lds0 + i * 1024), 16, 0, 0);
    gsrc += 128;
  }
  asm volatile("s_waitcnt vmcnt(0)" ::: "memory");
  __builtin_amdgcn_s_barrier();
  __builtin_amdgcn_sched_barrier(0);

  for (int s = 0; s < 64; ++s) {
    const int cur = s & 1;
    if (s < 63) {
      char* ldsn = (char*)&TILE[cur ^ 1][0] + wave * 8192;
#pragma unroll
      for (int i = 0; i < 8; i++)
        __builtin_amdgcn_global_load_lds(
            (const __attribute__((address_space(1))) void*)(gsrc + (size_t)i * 65536),
            (__attribute__((address_space(3))) void*)(ldsn + i * 1024), 16, 0, 0);
      gsrc += 128;
    }

    const unsigned short* T = &TILE[cur][0];
    bf16x8 a_h[4], a_l[4], b_h[4], b_l[4];
#pragma unroll
    for (int t4 = 0; t4 < 4; t4++) {
      int ra = wr + t4 * 16 + m;
      int rb = wc + t4 * 16 + m;
      int sa = ra & 7, sb = rb & 7;
      a_h[t4] = *(const bf16x8*)&T[ra * 64 + ((kg ^ sa) << 3)];
      a_l[t4] = *(const bf16x8*)&T[ra * 64 + (((kg | 4) ^ sa) << 3)];
      b_h[t4] = *(const bf16x8*)&T[8192 + rb * 64 + ((kg ^ sb) << 3)];
      b_l[t4] = *(const bf16x8*)&T[8192 + rb * 64 + (((kg | 4) ^ sb) << 3)];
    }
#pragma unroll
    for (int ti = 0; ti < 4; ti++)
#pragma unroll
      for (int tj = 0; tj < 4; tj++) {
        acc[ti][tj] = __builtin_amdgcn_mfma_f32_16x16x32_bf16(a_h[ti], b_h[tj], acc[ti][tj], 0, 0, 0);
        acc[ti][tj] = __builtin_amdgcn_mfma_f32_16x16x32_bf16(a_h[ti], b_l[tj], acc[ti][tj], 0, 0, 0);
        acc[ti][tj] = __builtin_amdgcn_mfma_f32_16x16x32_bf16(a_l[ti], b_h[tj], acc[ti][tj], 0, 0, 0);
      }

    // wait only for THIS wave's prefetch (had the whole compute phase to land), then sync
    asm volatile("s_waitcnt vmcnt(0)" ::: "memory");
    __builtin_amdgcn_s_barrier();
    __builtin_amdgcn_sched_barrier(0);
  }

  // epilogue: D2[i][j] = max(fn[i]+fn[j]-2*dot, 0); direct + mirror stores
  // C/D layout: col = lane&15, row = (lane>>4)*4 + reg
#pragma unroll
  for (int ti = 0; ti < 4; ti++) {
    int irow0 = ib + wr + ti * 16 + kg * 4;
    float4 fni = *(const float4*)&fn[irow0];
    float fniv[4] = {fni.x, fni.y, fni.z, fni.w};
#pragma unroll
    for (int tj = 0; tj < 4; tj++) {
      int jg = jb + wc + tj * 16 + m;
      float fnj = fn[jg];
      float val[4];
#pragma unroll
      for (int r = 0; r < 4; r++)
        val[r] = fmaxf(fniv[r] + fnj - 2.f * acc[ti][tj][r], 0.f);
#pragma unroll
      for (int r = 0; r < 4; r++)
        D2[(size_t)(irow0 + r) * N2 + jg] = val[r];
      if (bi != bj)
        *(float4*)&D2[(size_t)jg * N2 + irow0] = make_float4(val[0], val[1], val[2], val[3]);
    }
  }
}

// ---------------- z-gram logits via bf16 hi/lo MFMA (same structure, K=128 -> 4 slabs) ----------------
// Replaces the fp32 VALU GEMM (17.2 GFLOP at 157 TF vector ceiling) with the session-proven
// 3-pass hi/lo MFMA (residual ~1e-6 on O(1) logits). Epilogue applies the off-diag
// column permutation and /TEMPERATURE.
__global__ __launch_bounds__(256) void zgram_mfma_kernel(const unsigned short* __restrict__ zcomb,
                                                         float* __restrict__ out) {
  int bj = blockIdx.x, bi = blockIdx.y;
  const int ib = bi * 128, jb = bj * 128;

  __shared__ __attribute__((aligned(16))) unsigned short TILE[2][2 * 128 * 64];

  const int tid = threadIdx.x;
  const int lane = tid & 63;
  const int wave = tid >> 6;
  const int wr = (wave >> 1) * 64;
  const int wc = (wave & 1) * 64;
  const int m  = lane & 15;
  const int kg = lane >> 4;

  const int lrow8 = lane >> 3;
  const int lchk  = (lane & 7) ^ lrow8;
  const int grow0 = ((wave < 2) ? ib : jb) + (wave & 1) * 64;
  // zcomb row stride 512 B; 8-row step per load iter = 4096 B
  const char* gsrc = (const char*)zcomb + (size_t)(grow0 + lrow8) * 512 + (size_t)lchk * 16;

  f32x4 acc[4][4];
#pragma unroll
  for (int i = 0; i < 4; i++)
#pragma unroll
    for (int j = 0; j < 4; j++) acc[i][j] = (f32x4)0.f;

  {
    char* lds0 = (char*)&TILE[0][0] + wave * 8192;
#pragma unroll
    for (int i = 0; i < 8; i++)
      __builtin_amdgcn_global_load_lds(
          (const __attribute__((address_space(1))) void*)(gsrc + (size_t)i * 4096),
          (__attribute__((address_space(3))) void*)(lds0 + i * 1024), 16, 0, 0);
    gsrc += 128;
  }
  asm volatile("s_waitcnt vmcnt(0)" ::: "memory");
  __builtin_amdgcn_s_barrier();
  __builtin_amdgcn_sched_barrier(0);

  for (int s = 0; s < 4; ++s) {
    const int cur = s & 1;
    if (s < 3) {
      char* ldsn = (char*)&TILE[cur ^ 1][0] + wave * 8192;
#pragma unroll
      for (int i = 0; i < 8; i++)
        __builtin_amdgcn_global_load_lds(
            (const __attribute__((address_space(1))) void*)(gsrc + (size_t)i * 4096),
            (__attribute__((address_space(3))) void*)(ldsn + i * 1024), 16, 0, 0);
      gsrc += 128;
    }

    const unsigned short* T = &TILE[cur][0];
    bf16x8 a_h[4], a_l[4], b_h[4], b_l[4];
#pragma unroll
    for (int t4 = 0; t4 < 4; t4++) {
      int ra = wr + t4 * 16 + m;
      int rb = wc + t4 * 16 + m;
      int sa = ra & 7, sb = rb & 7;
      a_h[t4] = *(const bf16x8*)&T[ra * 64 + ((kg ^ sa) << 3)];
      a_l[t4] = *(const bf16x8*)&T[ra * 64 + (((kg | 4) ^ sa) << 3)];
      b_h[t4] = *(const bf16x8*)&T[8192 + rb * 64 + ((kg ^ sb) << 3)];
      b_l[t4] = *(const bf16x8*)&T[8192 + rb * 64 + (((kg | 4) ^ sb) << 3)];
    }
#pragma unroll
    for (int ti = 0; ti < 4; ti++)
#pragma unroll
      for (int tj = 0; tj < 4; tj++) {
        acc[ti][tj] = __builtin_amdgcn_mfma_f32_16x16x32_bf16(a_h[ti], b_h[tj], acc[ti][tj], 0, 0, 0);
        acc[ti][tj] = __builtin_amdgcn_mfma_f32_16x16x32_bf16(a_h[ti], b_l[tj], acc[ti][tj], 0, 0, 0);
        acc[ti][tj] = __builtin_amdgcn_mfma_f32_16x16x32_bf16(a_l[ti], b_h[tj], acc[ti][tj], 0, 0, 0);
      }

    asm volatile("s_waitcnt vmcnt(0)" ::: "memory");
    __builtin_amdgcn_s_barrier();
    __builtin_amdgcn_sched_barrier(0);
  }

  // epilogue: logits scatter with off-diag column permutation; lg = 2*dot (/TEMPERATURE=0.5)
  // C/D layout: col = lane&15, row = (lane>>4)*4 + reg
#pragma unroll
  for (int ti = 0; ti < 4; ti++) {
    int R0 = ib + wr + ti * 16 + kg * 4;
#pragma unroll
    for (int tj = 0; tj < 4; tj++) {
      int C = jb + wc + tj * 16 + m;
#pragma unroll
      for (int r = 0; r < 4; r++) {
        int R = R0 + r;
        if (C == R) continue;
        float lg = 2.f * acc[ti][tj][r];
        int col;
        if (R < B_) col = (C >= B_) ? (C - B_) : (B_ + C - (C > R ? 1 : 0));
        else        col = (C < B_) ? C : (C - (C > R ? 1 : 0));
        out[OFF_LOGITS + (size_t)R * NL + col] = lg;
      }
    }
  }
}

// ---------------- D2 via bf16 hi/lo split MFMA (fallback if ws too small) ----------------
#define LSTR 40   // padded LDS row stride in shorts (80 B)
__global__ __launch_bounds__(256) void d2_gemm_mfma_kernel(const float* __restrict__ f0,
                                                           const float* __restrict__ f1,
                                                           const float* __restrict__ fn,
                                                           float* __restrict__ D2) {
  int bj = blockIdx.x, bi = blockIdx.y;
  if (bi > bj) return;
  const int ib = bi * 128, jb = bj * 128;
  const float* Ab = (ib < B_) ? f0 + (size_t)ib * DF : f1 + (size_t)(ib - B_) * DF;
  const float* Bb = (jb < B_) ? f0 + (size_t)jb * DF : f1 + (size_t)(jb - B_) * DF;

  __shared__ __attribute__((aligned(16))) unsigned short Ah[128 * LSTR];
  __shared__ __attribute__((aligned(16))) unsigned short Al[128 * LSTR];
  __shared__ __attribute__((aligned(16))) unsigned short Bh[128 * LSTR];
  __shared__ __attribute__((aligned(16))) unsigned short Bl[128 * LSTR];

  const int tid = threadIdx.x;
  const int lane = tid & 63;
  const int wave = tid >> 6;
  const int wr = (wave >> 1) * 64;
  const int wc = (wave & 1) * 64;
  const int m  = lane & 15;
  const int kg = lane >> 4;

  const int lrow = tid >> 1;
  const int lhalf = tid & 1;
  const float* arow = Ab + (size_t)lrow * DF + lhalf * 16;
  const float* brow = Bb + (size_t)lrow * DF + lhalf * 16;
  const int wbase = lrow * LSTR + lhalf * 16;

  f32x4 acc[4][4];
#pragma unroll
  for (int i = 0; i < 4; i++)
#pragma unroll
    for (int j = 0; j < 4; j++) acc[i][j] = (f32x4)0.f;

  for (int k0 = 0; k0 < DF; k0 += 32) {
    float av[16], bv[16];
#pragma unroll
    for (int q = 0; q < 4; q++) {
      float4 t = *(const float4*)(arow + k0 + q * 4);
      av[q * 4 + 0] = t.x; av[q * 4 + 1] = t.y; av[q * 4 + 2] = t.z; av[q * 4 + 3] = t.w;
    }
#pragma unroll
    for (int q = 0; q < 4; q++) {
      float4 t = *(const float4*)(brow + k0 + q * 4);
      bv[q * 4 + 0] = t.x; bv[q * 4 + 1] = t.y; bv[q * 4 + 2] = t.z; bv[q * 4 + 3] = t.w;
    }

    __syncthreads();

    ushort8 ah0, ah1, al0, al1, bh0, bh1, bl0, bl1;
#pragma unroll
    for (int j = 0; j < 8; j++) {
      unsigned short h = f2bf(av[j]);     ah0[j] = h; al0[j] = f2bf(av[j] - bf2f(h));
      unsigned short h2 = f2bf(av[j + 8]); ah1[j] = h2; al1[j] = f2bf(av[j + 8] - bf2f(h2));
      unsigned short h3 = f2bf(bv[j]);     bh0[j] = h3; bl0[j] = f2bf(bv[j] - bf2f(h3));
      unsigned short h4 = f2bf(bv[j + 8]); bh1[j] = h4; bl1[j] = f2bf(bv[j + 8] - bf2f(h4));
    }
    *(ushort8*)&Ah[wbase] = ah0;     *(ushort8*)&Ah[wbase + 8] = ah1;
    *(ushort8*)&Al[wbase] = al0;     *(ushort8*)&Al[wbase + 8] = al1;
    *(ushort8*)&Bh[wbase] = bh0;     *(ushort8*)&Bh[wbase + 8] = bh1;
    *(ushort8*)&Bl[wbase] = bl0;     *(ushort8*)&Bl[wbase + 8] = bl1;

    __syncthreads();

    bf16x8 a_h[4], a_l[4], b_h[4], b_l[4];
#pragma unroll
    for (int t4 = 0; t4 < 4; t4++) {
      int aoff = (wr + t4 * 16 + m) * LSTR + kg * 8;
      int boff = (wc + t4 * 16 + m) * LSTR + kg * 8;
      a_h[t4] = *(const bf16x8*)&Ah[aoff];
      a_l[t4] = *(const bf16x8*)&Al[aoff];
      b_h[t4] = *(const bf16x8*)&Bh[boff];
      b_l[t4] = *(const bf16x8*)&Bl[boff];
    }
#pragma unroll
    for (int ti = 0; ti < 4; ti++)
#pragma unroll
      for (int tj = 0; tj < 4; tj++) {
        acc[ti][tj] = __builtin_amdgcn_mfma_f32_16x16x32_bf16(a_h[ti], b_h[tj], acc[ti][tj], 0, 0, 0);
        acc[ti][tj] = __builtin_amdgcn_mfma_f32_16x16x32_bf16(a_h[ti], b_l[tj], acc[ti][tj], 0, 0, 0);
        acc[ti][tj] = __builtin_amdgcn_mfma_f32_16x16x32_bf16(a_l[ti], b_h[tj], acc[ti][tj], 0, 0, 0);
      }
  }

#pragma unroll
  for (int ti = 0; ti < 4; ti++) {
    int irow0 = ib + wr + ti * 16 + kg * 4;
    float4 fni = *(const float4*)&fn[irow0];
    float fniv[4] = {fni.x, fni.y, fni.z, fni.w};
#pragma unroll
    for (int tj = 0; tj < 4; tj++) {
      int jg = jb + wc + tj * 16 + m;
      float fnj = fn[jg];
      float val[4];
#pragma unroll
      for (int r = 0; r < 4; r++)
        val[r] = fmaxf(fniv[r] + fnj - 2.f * acc[ti][tj][r], 0.f);
#pragma unroll
      for (int r = 0; r < 4; r++)
        D2[(size_t)(irow0 + r) * N2 + jg] = val[r];
      if (bi != bj)
        *(float4*)&D2[(size_t)jg * N2 + irow0] = make_float4(val[0], val[1], val[2], val[3]);
    }
  }
}

// ---------------- per-row 513-smallest + LID (R1-verified version) ----------------
__global__ __launch_bounds__(256) void select_lid_kernel(const float* __restrict__ D2,
                                                         float* __restrict__ out) {
  int r = blockIdx.x, tid = threadIdx.x;
  const float* row = D2 + (size_t)r * N2;
  unsigned key[32];
#pragma unroll
  for (int j = 0; j < 32; j++) {
    float v = fmaxf(row[tid + j * 256], 0.f);   // clip(d2, 0); nonneg floats: bits are order-preserving
    key[j] = __float_as_uint(v);
  }
  __shared__ int wcnt[32][4];
  __shared__ int pref[256];
  __shared__ unsigned cand[512];
  __shared__ float rr[8];

  // bit-descent: T = max{x : count(key < x) <= 512} = 513th smallest key
  unsigned T = 0;
  for (int b = 30; b >= 0; b--) {
    unsigned t = T | (1u << b);
    int c = 0;
#pragma unroll
    for (int j = 0; j < 32; j++) c += (key[j] < t) ? 1 : 0;
    for (int off = 32; off; off >>= 1) c += __shfl_down(c, off, 64);
    if ((tid & 63) == 0) wcnt[b][tid >> 6] = c;
    __syncthreads();
    int tot = wcnt[b][0] + wcnt[b][1] + wcnt[b][2] + wcnt[b][3];
    if (tot <= 512) T = t;
  }

  // gather strictly-less-than-T candidates (count c0 <= 512)
  int n_t = 0;
#pragma unroll
  for (int j = 0; j < 32; j++) n_t += (key[j] < T) ? 1 : 0;
  pref[tid] = n_t;
  __syncthreads();
  for (int s = 1; s < 256; s <<= 1) {
    int v = (tid >= s) ? pref[tid - s] : 0;
    __syncthreads();
    pref[tid] += v;
    __syncthreads();
  }
  int c0 = pref[255];
  int base = pref[tid] - n_t;
  cand[tid] = 0xFFFFFFFFu;
  cand[tid + 256] = 0xFFFFFFFFu;
  __syncthreads();
  {
    int idx = base;
#pragma unroll
    for (int j = 0; j < 32; j++)
      if (key[j] < T) cand[idx++] = key[j];
  }
  __syncthreads();

  // bitonic sort 512 ascending
  for (int k = 2; k <= 512; k <<= 1) {
    for (int j = k >> 1; j > 0; j >>= 1) {
      int i = ((tid & ~(j - 1)) << 1) | (tid & (j - 1));
      int p = i | j;
      bool up = (i & k) == 0;
      unsigned a = cand[i], b2 = cand[p];
      if ((a > b2) == up) { cand[i] = b2; cand[p] = a; }
      __syncthreads();
    }
  }

  // sorted 513-ascending = cand[0..c0) ++ (513-c0) copies of T; element 0 is the self (dropped)
  float d32  = sqrtf(__uint_as_float(32  < c0 ? cand[32]  : T));
  float d512 = sqrtf(__uint_as_float(512 < c0 ? cand[512] : T));
  int i1 = tid + 1, i2 = tid + 257;
  float di1 = sqrtf(__uint_as_float(i1 < c0 ? cand[i1] : T));
  float di2 = sqrtf(__uint_as_float(i2 < c0 ? cand[i2] : T));
  float s32 = (i1 <= 32) ? logf(di1 / d32 + 1e-12f) : 0.f;
  float s512 = logf(di1 / d512 + 1e-12f) + logf(di2 / d512 + 1e-12f);
  for (int off = 32; off; off >>= 1) {
    s32 += __shfl_down(s32, off, 64);
    s512 += __shfl_down(s512, off, 64);
  }
  if ((tid & 63) == 0) { rr[tid >> 6] = s32; rr[4 + (tid >> 6)] = s512; }
  __syncthreads();
  if (tid == 0) {
    float S32 = rr[0] + rr[1] + rr[2] + rr[3];
    float S512 = rr[4] + rr[5] + rr[6] + rr[7];
    out[OFF_L32 + r] = -32.f / S32;
    out[OFF_L512 + r] = -512.f / S512;
  }
}

// ---------------- logits = reshuffled z-gram / T (fp32 VALU; fallback path only) ----------------
__global__ __launch_bounds__(256) void zgram_logits_kernel(const float* __restrict__ zn,
                                                           float* __restrict__ out) {
  int bj = blockIdx.x, bi = blockIdx.y;
  const int ib = bi * 128, jb = bj * 128;
  const float* Ab = zn + (size_t)ib * DZ;
  const float* Bb = zn + (size_t)jb * DZ;

  __shared__ __attribute__((aligned(16))) float As[16][128];
  __shared__ __attribute__((aligned(16))) float Bs[16][128];

  int tid = threadIdx.x;
  int tx = tid & 15, ty = tid >> 4;
  int lrow = tid >> 1;
  int lk = (tid & 1) * 8;

  float acc[8][8];
#pragma unroll
  for (int i = 0; i < 8; i++)
#pragma unroll
    for (int j = 0; j < 8; j++) acc[i][j] = 0.f;

  for (int k0 = 0; k0 < DZ; k0 += 16) {
    float4 a0 = *(const float4*)(Ab + (size_t)lrow * DZ + k0 + lk);
    float4 a1 = *(const float4*)(Ab + (size_t)lrow * DZ + k0 + lk + 4);
    float4 b0 = *(const float4*)(Bb + (size_t)lrow * DZ + k0 + lk);
    float4 b1 = *(const float4*)(Bb + (size_t)lrow * DZ + k0 + lk + 4);
    __syncthreads();
    As[lk + 0][lrow] = a0.x; As[lk + 1][lrow] = a0.y; As[lk + 2][lrow] = a0.z; As[lk + 3][lrow] = a0.w;
    As[lk + 4][lrow] = a1.x; As[lk + 5][lrow] = a1.y; As[lk + 6][lrow] = a1.z; As[lk + 7][lrow] = a1.w;
    Bs[lk + 0][lrow] = b0.x; Bs[lk + 1][lrow] = b0.y; Bs[lk + 2][lrow] = b0.z; Bs[lk + 3][lrow] = b0.w;
    Bs[lk + 4][lrow] = b1.x; Bs[lk + 5][lrow] = b1.y; Bs[lk + 6][lrow] = b1.z; Bs[lk + 7][lrow] = b1.w;
    __syncthreads();
#pragma unroll
    for (int kk = 0; kk < 16; kk++) {
      float4 av0 = *(const float4*)&As[kk][ty * 8];
      float4 av1 = *(const float4*)&As[kk][ty * 8 + 4];
      float4 bv0 = *(const float4*)&Bs[kk][tx * 4];
      float4 bv1 = *(const float4*)&Bs[kk][tx * 4 + 64];
      float a_[8] = {av0.x, av0.y, av0.z, av0.w, av1.x, av1.y, av1.z, av1.w};
      float b_[8] = {bv0.x, bv0.y, bv0.z, bv0.w, bv1.x, bv1.y, bv1.z, bv1.w};
#pragma unroll
      for (int v = 0; v < 8; v++)
#pragma unroll
        for (int u = 0; u < 8; u++) acc[v][u] += a_[v] * b_[u];
    }
  }

#pragma unroll
  for (int v = 0; v < 8; v++) {
    int rrow = ib + ty * 8 + v;
#pragma unroll
    for (int u = 0; u < 8; u++) {
      int c = jb + tx * 4 + (u & 3) + (u >> 2) * 64;
      if (c == rrow) continue;
      float lg = 2.f * acc[v][u];  // /TEMPERATURE(0.5)
      int col;
      if (rrow < B_) col = (c >= B_) ? (c - B_) : (B_ + c - (c > rrow ? 1 : 0));
      else           col = (c < B_) ? c : (c - (c > rrow ? 1 : 0));
      out[OFF_LOGITS + (size_t)rrow * NL + col] = lg;
    }
  }
}

// ---------------- labels ----------------
__global__ void labels_kernel(float* __restrict__ out) {
  int i = blockIdx.x * 256 + threadIdx.x;
  if (i < N2) out[OFF_LAB + i] = (float)(i & (B_ - 1));
}

// ---------------- per-row loss ----------------
__global__ __launch_bounds__(256) void loss_row_kernel(const float* __restrict__ out,
                                                       float* __restrict__ lossp) {
  int r = blockIdx.x, tid = threadIdx.x;
  const float* row = out + OFF_LOGITS + (size_t)r * NL;
  __shared__ __attribute__((aligned(16))) float buf[NL];
  __shared__ float red[4];
  float m = -1e30f;
  for (int j = tid; j < NL; j += 256) { float v = row[j]; buf[j] = v; m = fmaxf(m, v); }
  for (int off = 32; off; off >>= 1) m = fmaxf(m, __shfl_down(m, off, 64));
  if ((tid & 63) == 0) red[tid >> 6] = m;
  __syncthreads();
  m = fmaxf(fmaxf(red[0], red[1]), fmaxf(red[2], red[3]));
  float s = 0.f;
  for (int j = tid; j < NL; j += 256) s += expf(buf[j] - m);
  for (int off = 32; off; off >>= 1) s += __shfl_down(s, off, 64);
  __syncthreads();
  if ((tid & 63) == 0) red[tid >> 6] = s;
  __syncthreads();
  if (tid == 0) {
    float S = red[0] + red[1] + red[2] + red[3];
    lossp[r] = m + logf(S) - buf[r & (B_ - 1)];
  }
}

// ---------------- final mean ----------------
__global__ void finalize_kernel(const float* __restrict__ lossp, float* __restrict__ out) {
  int tid = threadIdx.x;
  float s = 0.f;
  for (int j = tid; j < N2; j += 256) s += lossp[j];
  for (int off = 32; off; off >>= 1) s += __shfl_down(s, off, 64);
  __shared__ float red[4];
  if ((tid & 63) == 0) red[tid >> 6] = s;
  __syncthreads();
  if (tid == 0) out[0] = (red[0] + red[1] + red[2] + red[3]) / (float)N2;
}

extern "C" void kernel_launch(void* const* d_in, const int* in_sizes, int n_in,
                              void* d_out, int out_size, void* d_ws, size_t ws_size,
                              hipStream_t stream) {
  const float* z0 = (const float*)d_in[0];
  const float* z1 = (const float*)d_in[1];
  const float* f0 = (const float*)d_in[2];
  const float* f1 = (const float*)d_in[3];
  float* out = (float*)d_out;
  float* ws = (float*)d_ws;
  float* zn = ws + WS_ZN;
  float* fn = ws + WS_FN;
  float* lp = ws + WS_LP;
  float* D2 = out;  // scratch overlay on d_out[0 .. N2*N2)

  const size_t need_bytes = ((size_t)WS_ZCOMB + (size_t)N2 * 128) * sizeof(float);  // ~75.4 MB
  dim3 g(64, 64);

  if (ws_size >= need_bytes) {
    unsigned short* fcomb = (unsigned short*)(ws + WS_FCOMB);
    unsigned short* zcomb = (unsigned short*)(ws + WS_ZCOMB);
    convert_kernel<<<N2, 256, 0, stream>>>(f0, f1, fcomb, fn);  // fuses fnorm
    znorm2_kernel<<<N2, 128, 0, stream>>>(z0, z1, zcomb);
    d2_gemm_pre_kernel<<<g, 256, 0, stream>>>(fcomb, fn, D2);
    select_lid_kernel<<<N2, 256, 0, stream>>>(D2, out);       // lids -> final slots (past D2)
    zgram_mfma_kernel<<<g, 256, 0, stream>>>(zcomb, out);     // overwrites D2 scratch with logits
  } else {
    fnorm_kernel<<<N2, 256, 0, stream>>>(f0, f1, fn);
    znorm_kernel<<<N2, 128, 0, stream>>>(z0, z1, zn);
    d2_gemm_mfma_kernel<<<g, 256, 0, stream>>>(f0, f1, fn, D2);
    select_lid_kernel<<<N2, 256, 0, stream>>>(D2, out);
    zgram_logits_kernel<<<g, 256, 0, stream>>>(zn, out);
  }

  labels_kernel<<<(N2 + 255) / 256, 256, 0, stream>>>(out);
  loss_row_kernel<<<N2, 256, 0, stream>>>(out, lp);
  finalize_kernel<<<1, 256, 0, stream>>>(lp, out);
}

// Round 6
// 1028.473 us; speedup vs baseline: 1.4116x; 1.0970x over previous
//
#include <hip/hip_runtime.h>
#include <math.h>

#define B_   4096
#define DZ   128
#define DF   2048
#define N2   8192            // 2*B_
#define NL   8191            // 2*B_ - 1

// d_out layout (floats): [loss(1)][logits(8192*8191)][labels(8192)][lids32(8192)][lids512(8192)]
#define OFF_LOGITS 1
#define OFF_LAB  (1 + (size_t)N2 * NL)      // 67100673
#define OFF_L32  (OFF_LAB + N2)             // 67108865
#define OFF_L512 (OFF_L32 + N2)             // 67117057
// D2 scratch overlays d_out[0 .. N2*N2) = [0, 67108864) — disjoint from lids slots.

// ws layout (floats)
#define WS_ZN 0
#define WS_FN ((size_t)N2 * DZ)             // 1048576
#define WS_LP (WS_FN + N2)
#define WS_FCOMB (WS_LP + N2)               // bf16 hi/lo precomp: N2*DF floats (= N2*DF*2 shorts)
#define WS_ZCOMB (WS_FCOMB + (size_t)N2 * DF)  // z bf16 hi/lo: N2*128 floats (= N2*256 shorts)

typedef __attribute__((ext_vector_type(8))) __bf16 bf16x8;
typedef __attribute__((ext_vector_type(8))) unsigned short ushort8;
typedef __attribute__((ext_vector_type(4))) float f32x4;

// round-to-nearest-even fp32 -> bf16 bits (inputs are finite Gaussians; no NaN path needed)
__device__ __forceinline__ unsigned short f2bf(float f) {
  unsigned u = __float_as_uint(f);
  return (unsigned short)((u + 0x7FFFu + ((u >> 16) & 1u)) >> 16);
}
__device__ __forceinline__ float bf2f(unsigned short h) {
  return __uint_as_float(((unsigned)h) << 16);
}

// ---------------- row norms of f (||f_i||^2) — fallback path only ----------------
__global__ __launch_bounds__(256) void fnorm_kernel(const float* __restrict__ f0,
                                                    const float* __restrict__ f1,
                                                    float* __restrict__ fn) {
  int r = blockIdx.x;
  const float* row = (r < B_) ? f0 + (size_t)r * DF : f1 + (size_t)(r - B_) * DF;
  float s = 0.f;
  for (int j = threadIdx.x; j < DF; j += 256) { float v = row[j]; s += v * v; }
  for (int off = 32; off; off >>= 1) s += __shfl_down(s, off, 64);
  __shared__ float red[4];
  if ((threadIdx.x & 63) == 0) red[threadIdx.x >> 6] = s;
  __syncthreads();
  if (threadIdx.x == 0) fn[r] = red[0] + red[1] + red[2] + red[3];
}

// ---------------- fused: fp32 -> bf16 hi/lo precompute + row norms ----------------
// fcomb layout per row r: 64 slabs x 128 B; slab s = [hi(32 shorts) | lo(32 shorts)]
// covering k = s*32 .. s*32+32. Row byte stride = 8192.
__global__ __launch_bounds__(256) void convert_kernel(const float* __restrict__ f0,
                                                      const float* __restrict__ f1,
                                                      unsigned short* __restrict__ fcomb,
                                                      float* __restrict__ fn) {
  int r = blockIdx.x, t = threadIdx.x;
  const float* row = (r < B_) ? f0 + (size_t)r * DF : f1 + (size_t)(r - B_) * DF;
  float4 v0 = *(const float4*)(row + t * 8);
  float4 v1 = *(const float4*)(row + t * 8 + 4);
  float v[8] = {v0.x, v0.y, v0.z, v0.w, v1.x, v1.y, v1.z, v1.w};
  ushort8 h, l;
  float s = 0.f;
#pragma unroll
  for (int j = 0; j < 8; j++) {
    unsigned short hb = f2bf(v[j]);
    h[j] = hb;
    l[j] = f2bf(v[j] - bf2f(hb));
    s += v[j] * v[j];
  }
  unsigned short* rowp = fcomb + (size_t)r * (2 * DF);
  int slab = t >> 2, c = t & 3;           // thread covers hi chunk c, lo chunk 4+c of slab
  *(ushort8*)(rowp + slab * 64 + c * 8) = h;
  *(ushort8*)(rowp + slab * 64 + 32 + c * 8) = l;
  for (int off = 32; off; off >>= 1) s += __shfl_down(s, off, 64);
  __shared__ float red[4];
  if ((t & 63) == 0) red[t >> 6] = s;
  __syncthreads();
  if (t == 0) fn[r] = red[0] + red[1] + red[2] + red[3];
}

// ---------------- normalize z rows (fp32 out) — fallback path only ----------------
__global__ void znorm_kernel(const float* __restrict__ z0, const float* __restrict__ z1,
                             float* __restrict__ zn) {
  int r = blockIdx.x, t = threadIdx.x;  // 128 threads
  const float* row = (r < B_) ? z0 + (size_t)r * DZ : z1 + (size_t)(r - B_) * DZ;
  float v = row[t];
  float s = v * v;
  for (int off = 32; off; off >>= 1) s += __shfl_down(s, off, 64);
  __shared__ float red[2];
  if ((t & 63) == 0) red[t >> 6] = s;
  __syncthreads();
  float n = sqrtf(red[0] + red[1]);
  zn[(size_t)r * DZ + t] = v / fmaxf(n, 1e-12f);
}

// ---------------- normalize z rows -> bf16 hi/lo slabs (main path) ----------------
// zcomb layout per row r: 4 slabs x 128 B; slab s = [hi(32 shorts) | lo(32 shorts)]
// covering k = s*32 .. s*32+32. Row byte stride = 512.
__global__ void znorm2_kernel(const float* __restrict__ z0, const float* __restrict__ z1,
                              unsigned short* __restrict__ zcomb) {
  int r = blockIdx.x, t = threadIdx.x;  // 128 threads
  const float* row = (r < B_) ? z0 + (size_t)r * DZ : z1 + (size_t)(r - B_) * DZ;
  float v = row[t];
  float s = v * v;
  for (int off = 32; off; off >>= 1) s += __shfl_down(s, off, 64);
  __shared__ float red[2];
  if ((t & 63) == 0) red[t >> 6] = s;
  __syncthreads();
  float n = sqrtf(red[0] + red[1]);
  float vn = v / fmaxf(n, 1e-12f);
  unsigned short hb = f2bf(vn);
  unsigned short lb = f2bf(vn - bf2f(hb));
  unsigned short* rowp = zcomb + (size_t)r * 256;
  int slab = t >> 5, p = t & 31;
  rowp[slab * 64 + p] = hb;
  rowp[slab * 64 + 32 + p] = lb;
}

// ---------------- D2 GEMM, precomputed bf16 hi/lo, 2-phase pipelined (R3-verified) ----------------
__global__ __launch_bounds__(256) void d2_gemm_pre_kernel(const unsigned short* __restrict__ fcomb,
                                                          const float* __restrict__ fn,
                                                          float* __restrict__ D2) {
  int bj = blockIdx.x, bi = blockIdx.y;
  if (bi > bj) return;
  const int ib = bi * 128, jb = bj * 128;

  __shared__ __attribute__((aligned(16))) unsigned short TILE[2][2 * 128 * 64];

  const int tid = threadIdx.x;
  const int lane = tid & 63;
  const int wave = tid >> 6;
  const int wr = (wave >> 1) * 64;     // quadrant row base within tile
  const int wc = (wave & 1) * 64;      // quadrant col base within tile
  const int m  = lane & 15;            // frag row/col within 16
  const int kg = lane >> 4;            // k-group (0..3) -> k = kg*8 + j

  // staging: wave w covers LDS bytes [w*8192, (w+1)*8192): w0/w1 = A rows 0-63/64-127, w2/w3 = B.
  const int lrow8 = lane >> 3;                 // 0..7: row within 8-row stripe
  const int lchk  = (lane & 7) ^ lrow8;        // inverse-swizzled source chunk
  const int grow0 = ((wave < 2) ? ib : jb) + (wave & 1) * 64;
  const char* gsrc = (const char*)fcomb + (size_t)(grow0 + lrow8) * 8192 + (size_t)lchk * 16;

  f32x4 acc[4][4];
#pragma unroll
  for (int i = 0; i < 4; i++)
#pragma unroll
    for (int j = 0; j < 4; j++) acc[i][j] = (f32x4)0.f;

  // prologue: stage slab 0 into TILE[0]
  {
    char* lds0 = (char*)&TILE[0][0] + wave * 8192;
#pragma unroll
    for (int i = 0; i < 8; i++)
      __builtin_amdgcn_global_load_lds(
          (const __attribute__((address_space(1))) void*)(gsrc + (size_t)i * 65536),
          (__attribute__((address_space(3))) void*)(lds0 + i * 1024), 16, 0, 0);
    gsrc += 128;
  }
  asm volatile("s_waitcnt vmcnt(0)" ::: "memory");
  __builtin_amdgcn_s_barrier();
  __builtin_amdgcn_sched_barrier(0);

  for (int s = 0; s < 64; ++s) {
    const int cur = s & 1;
    if (s < 63) {
      char* ldsn = (char*)&TILE[cur ^ 1][0] + wave * 8192;
#pragma unroll
      for (int i = 0; i < 8; i++)
        __builtin_amdgcn_global_load_lds(
            (const __attribute__((address_space(1))) void*)(gsrc + (size_t)i * 65536),
            (__attribute__((address_space(3))) void*)(ldsn + i * 1024), 16, 0, 0);
      gsrc += 128;
    }

    const unsigned short* T = &TILE[cur][0];
    bf16x8 a_h[4], a_l[4], b_h[4], b_l[4];
#pragma unroll
    for (int t4 = 0; t4 < 4; t4++) {
      int ra = wr + t4 * 16 + m;
      int rb = wc + t4 * 16 + m;
      int sa = ra & 7, sb = rb & 7;
      a_h[t4] = *(const bf16x8*)&T[ra * 64 + ((kg ^ sa) << 3)];
      a_l[t4] = *(const bf16x8*)&T[ra * 64 + (((kg | 4) ^ sa) << 3)];
      b_h[t4] = *(const bf16x8*)&T[8192 + rb * 64 + ((kg ^ sb) << 3)];
      b_l[t4] = *(const bf16x8*)&T[8192 + rb * 64 + (((kg | 4) ^ sb) << 3)];
    }
#pragma unroll
    for (int ti = 0; ti < 4; ti++)
#pragma unroll
      for (int tj = 0; tj < 4; tj++) {
        acc[ti][tj] = __builtin_amdgcn_mfma_f32_16x16x32_bf16(a_h[ti], b_h[tj], acc[ti][tj], 0, 0, 0);
        acc[ti][tj] = __builtin_amdgcn_mfma_f32_16x16x32_bf16(a_h[ti], b_l[tj], acc[ti][tj], 0, 0, 0);
        acc[ti][tj] = __builtin_amdgcn_mfma_f32_16x16x32_bf16(a_l[ti], b_h[tj], acc[ti][tj], 0, 0, 0);
      }

    // wait only for THIS wave's prefetch (had the whole compute phase to land), then sync
    asm volatile("s_waitcnt vmcnt(0)" ::: "memory");
    __builtin_amdgcn_s_barrier();
    __builtin_amdgcn_sched_barrier(0);
  }

  // epilogue: D2[i][j] = max(fn[i]+fn[j]-2*dot, 0); direct + mirror stores
  // C/D layout: col = lane&15, row = (lane>>4)*4 + reg
#pragma unroll
  for (int ti = 0; ti < 4; ti++) {
    int irow0 = ib + wr + ti * 16 + kg * 4;
    float4 fni = *(const float4*)&fn[irow0];
    float fniv[4] = {fni.x, fni.y, fni.z, fni.w};
#pragma unroll
    for (int tj = 0; tj < 4; tj++) {
      int jg = jb + wc + tj * 16 + m;
      float fnj = fn[jg];
      float val[4];
#pragma unroll
      for (int r = 0; r < 4; r++)
        val[r] = fmaxf(fniv[r] + fnj - 2.f * acc[ti][tj][r], 0.f);
#pragma unroll
      for (int r = 0; r < 4; r++)
        D2[(size_t)(irow0 + r) * N2 + jg] = val[r];
      if (bi != bj)
        *(float4*)&D2[(size_t)jg * N2 + irow0] = make_float4(val[0], val[1], val[2], val[3]);
    }
  }
}

// ---------------- z-gram logits via bf16 hi/lo MFMA (R4-verified) ----------------
__global__ __launch_bounds__(256) void zgram_mfma_kernel(const unsigned short* __restrict__ zcomb,
                                                         float* __restrict__ out) {
  int bj = blockIdx.x, bi = blockIdx.y;
  const int ib = bi * 128, jb = bj * 128;

  __shared__ __attribute__((aligned(16))) unsigned short TILE[2][2 * 128 * 64];

  const int tid = threadIdx.x;
  const int lane = tid & 63;
  const int wave = tid >> 6;
  const int wr = (wave >> 1) * 64;
  const int wc = (wave & 1) * 64;
  const int m  = lane & 15;
  const int kg = lane >> 4;

  const int lrow8 = lane >> 3;
  const int lchk  = (lane & 7) ^ lrow8;
  const int grow0 = ((wave < 2) ? ib : jb) + (wave & 1) * 64;
  // zcomb row stride 512 B; 8-row step per load iter = 4096 B
  const char* gsrc = (const char*)zcomb + (size_t)(grow0 + lrow8) * 512 + (size_t)lchk * 16;

  f32x4 acc[4][4];
#pragma unroll
  for (int i = 0; i < 4; i++)
#pragma unroll
    for (int j = 0; j < 4; j++) acc[i][j] = (f32x4)0.f;

  {
    char* lds0 = (char*)&TILE[0][0] + wave * 8192;
#pragma unroll
    for (int i = 0; i < 8; i++)
      __builtin_amdgcn_global_load_lds(
          (const __attribute__((address_space(1))) void*)(gsrc + (size_t)i * 4096),
          (__attribute__((address_space(3))) void*)(lds0 + i * 1024), 16, 0, 0);
    gsrc += 128;
  }
  asm volatile("s_waitcnt vmcnt(0)" ::: "memory");
  __builtin_amdgcn_s_barrier();
  __builtin_amdgcn_sched_barrier(0);

  for (int s = 0; s < 4; ++s) {
    const int cur = s & 1;
    if (s < 3) {
      char* ldsn = (char*)&TILE[cur ^ 1][0] + wave * 8192;
#pragma unroll
      for (int i = 0; i < 8; i++)
        __builtin_amdgcn_global_load_lds(
            (const __attribute__((address_space(1))) void*)(gsrc + (size_t)i * 4096),
            (__attribute__((address_space(3))) void*)(ldsn + i * 1024), 16, 0, 0);
      gsrc += 128;
    }

    const unsigned short* T = &TILE[cur][0];
    bf16x8 a_h[4], a_l[4], b_h[4], b_l[4];
#pragma unroll
    for (int t4 = 0; t4 < 4; t4++) {
      int ra = wr + t4 * 16 + m;
      int rb = wc + t4 * 16 + m;
      int sa = ra & 7, sb = rb & 7;
      a_h[t4] = *(const bf16x8*)&T[ra * 64 + ((kg ^ sa) << 3)];
      a_l[t4] = *(const bf16x8*)&T[ra * 64 + (((kg | 4) ^ sa) << 3)];
      b_h[t4] = *(const bf16x8*)&T[8192 + rb * 64 + ((kg ^ sb) << 3)];
      b_l[t4] = *(const bf16x8*)&T[8192 + rb * 64 + (((kg | 4) ^ sb) << 3)];
    }
#pragma unroll
    for (int ti = 0; ti < 4; ti++)
#pragma unroll
      for (int tj = 0; tj < 4; tj++) {
        acc[ti][tj] = __builtin_amdgcn_mfma_f32_16x16x32_bf16(a_h[ti], b_h[tj], acc[ti][tj], 0, 0, 0);
        acc[ti][tj] = __builtin_amdgcn_mfma_f32_16x16x32_bf16(a_h[ti], b_l[tj], acc[ti][tj], 0, 0, 0);
        acc[ti][tj] = __builtin_amdgcn_mfma_f32_16x16x32_bf16(a_l[ti], b_h[tj], acc[ti][tj], 0, 0, 0);
      }

    asm volatile("s_waitcnt vmcnt(0)" ::: "memory");
    __builtin_amdgcn_s_barrier();
    __builtin_amdgcn_sched_barrier(0);
  }

  // epilogue: logits scatter with off-diag column permutation; lg = 2*dot (/TEMPERATURE=0.5)
  // C/D layout: col = lane&15, row = (lane>>4)*4 + reg
#pragma unroll
  for (int ti = 0; ti < 4; ti++) {
    int R0 = ib + wr + ti * 16 + kg * 4;
#pragma unroll
    for (int tj = 0; tj < 4; tj++) {
      int C = jb + wc + tj * 16 + m;
#pragma unroll
      for (int r = 0; r < 4; r++) {
        int R = R0 + r;
        if (C == R) continue;
        float lg = 2.f * acc[ti][tj][r];
        int col;
        if (R < B_) col = (C >= B_) ? (C - B_) : (B_ + C - (C > R ? 1 : 0));
        else        col = (C < B_) ? C : (C - (C > R ? 1 : 0));
        out[OFF_LOGITS + (size_t)R * NL + col] = lg;
      }
    }
  }
}

// ---------------- D2 via bf16 hi/lo split MFMA (fallback if ws too small) ----------------
#define LSTR 40   // padded LDS row stride in shorts (80 B)
__global__ __launch_bounds__(256) void d2_gemm_mfma_kernel(const float* __restrict__ f0,
                                                           const float* __restrict__ f1,
                                                           const float* __restrict__ fn,
                                                           float* __restrict__ D2) {
  int bj = blockIdx.x, bi = blockIdx.y;
  if (bi > bj) return;
  const int ib = bi * 128, jb = bj * 128;
  const float* Ab = (ib < B_) ? f0 + (size_t)ib * DF : f1 + (size_t)(ib - B_) * DF;
  const float* Bb = (jb < B_) ? f0 + (size_t)jb * DF : f1 + (size_t)(jb - B_) * DF;

  __shared__ __attribute__((aligned(16))) unsigned short Ah[128 * LSTR];
  __shared__ __attribute__((aligned(16))) unsigned short Al[128 * LSTR];
  __shared__ __attribute__((aligned(16))) unsigned short Bh[128 * LSTR];
  __shared__ __attribute__((aligned(16))) unsigned short Bl[128 * LSTR];

  const int tid = threadIdx.x;
  const int lane = tid & 63;
  const int wave = tid >> 6;
  const int wr = (wave >> 1) * 64;
  const int wc = (wave & 1) * 64;
  const int m  = lane & 15;
  const int kg = lane >> 4;

  const int lrow = tid >> 1;
  const int lhalf = tid & 1;
  const float* arow = Ab + (size_t)lrow * DF + lhalf * 16;
  const float* brow = Bb + (size_t)lrow * DF + lhalf * 16;
  const int wbase = lrow * LSTR + lhalf * 16;

  f32x4 acc[4][4];
#pragma unroll
  for (int i = 0; i < 4; i++)
#pragma unroll
    for (int j = 0; j < 4; j++) acc[i][j] = (f32x4)0.f;

  for (int k0 = 0; k0 < DF; k0 += 32) {
    float av[16], bv[16];
#pragma unroll
    for (int q = 0; q < 4; q++) {
      float4 t = *(const float4*)(arow + k0 + q * 4);
      av[q * 4 + 0] = t.x; av[q * 4 + 1] = t.y; av[q * 4 + 2] = t.z; av[q * 4 + 3] = t.w;
    }
#pragma unroll
    for (int q = 0; q < 4; q++) {
      float4 t = *(const float4*)(brow + k0 + q * 4);
      bv[q * 4 + 0] = t.x; bv[q * 4 + 1] = t.y; bv[q * 4 + 2] = t.z; bv[q * 4 + 3] = t.w;
    }

    __syncthreads();

    ushort8 ah0, ah1, al0, al1, bh0, bh1, bl0, bl1;
#pragma unroll
    for (int j = 0; j < 8; j++) {
      unsigned short h = f2bf(av[j]);     ah0[j] = h; al0[j] = f2bf(av[j] - bf2f(h));
      unsigned short h2 = f2bf(av[j + 8]); ah1[j] = h2; al1[j] = f2bf(av[j + 8] - bf2f(h2));
      unsigned short h3 = f2bf(bv[j]);     bh0[j] = h3; bl0[j] = f2bf(bv[j] - bf2f(h3));
      unsigned short h4 = f2bf(bv[j + 8]); bh1[j] = h4; bl1[j] = f2bf(bv[j + 8] - bf2f(h4));
    }
    *(ushort8*)&Ah[wbase] = ah0;     *(ushort8*)&Ah[wbase + 8] = ah1;
    *(ushort8*)&Al[wbase] = al0;     *(ushort8*)&Al[wbase + 8] = al1;
    *(ushort8*)&Bh[wbase] = bh0;     *(ushort8*)&Bh[wbase + 8] = bh1;
    *(ushort8*)&Bl[wbase] = bl0;     *(ushort8*)&Bl[wbase + 8] = bl1;

    __syncthreads();

    bf16x8 a_h[4], a_l[4], b_h[4], b_l[4];
#pragma unroll
    for (int t4 = 0; t4 < 4; t4++) {
      int aoff = (wr + t4 * 16 + m) * LSTR + kg * 8;
      int boff = (wc + t4 * 16 + m) * LSTR + kg * 8;
      a_h[t4] = *(const bf16x8*)&Ah[aoff];
      a_l[t4] = *(const bf16x8*)&Al[aoff];
      b_h[t4] = *(const bf16x8*)&Bh[boff];
      b_l[t4] = *(const bf16x8*)&Bl[boff];
    }
#pragma unroll
    for (int ti = 0; ti < 4; ti++)
#pragma unroll
      for (int tj = 0; tj < 4; tj++) {
        acc[ti][tj] = __builtin_amdgcn_mfma_f32_16x16x32_bf16(a_h[ti], b_h[tj], acc[ti][tj], 0, 0, 0);
        acc[ti][tj] = __builtin_amdgcn_mfma_f32_16x16x32_bf16(a_h[ti], b_l[tj], acc[ti][tj], 0, 0, 0);
        acc[ti][tj] = __builtin_amdgcn_mfma_f32_16x16x32_bf16(a_l[ti], b_h[tj], acc[ti][tj], 0, 0, 0);
      }
  }

#pragma unroll
  for (int ti = 0; ti < 4; ti++) {
    int irow0 = ib + wr + ti * 16 + kg * 4;
    float4 fni = *(const float4*)&fn[irow0];
    float fniv[4] = {fni.x, fni.y, fni.z, fni.w};
#pragma unroll
    for (int tj = 0; tj < 4; tj++) {
      int jg = jb + wc + tj * 16 + m;
      float fnj = fn[jg];
      float val[4];
#pragma unroll
      for (int r = 0; r < 4; r++)
        val[r] = fmaxf(fniv[r] + fnj - 2.f * acc[ti][tj][r], 0.f);
#pragma unroll
      for (int r = 0; r < 4; r++)
        D2[(size_t)(irow0 + r) * N2 + jg] = val[r];
      if (bi != bj)
        *(float4*)&D2[(size_t)jg * N2 + irow0] = make_float4(val[0], val[1], val[2], val[3]);
    }
  }
}

// ---------------- per-row 513-smallest + LID (R1 algorithm; float4 key loads) ----------------
// Load change only: 8 x float4 (16B, aligned: D2 rows are 16B-aligned) instead of 32 scalars.
// Per-thread key multiset differs in ORDER only; descent counts and post-sort ranks are
// order-invariant -> outputs bit-identical to the scalar-load version.
__global__ __launch_bounds__(256) void select_lid_kernel(const float* __restrict__ D2,
                                                         float* __restrict__ out) {
  int r = blockIdx.x, tid = threadIdx.x;
  const float* row = D2 + (size_t)r * N2;
  unsigned key[32];
#pragma unroll
  for (int j8 = 0; j8 < 8; j8++) {
    float4 v = *(const float4*)(row + (size_t)j8 * 1024 + tid * 4);
    key[j8 * 4 + 0] = __float_as_uint(fmaxf(v.x, 0.f));
    key[j8 * 4 + 1] = __float_as_uint(fmaxf(v.y, 0.f));
    key[j8 * 4 + 2] = __float_as_uint(fmaxf(v.z, 0.f));
    key[j8 * 4 + 3] = __float_as_uint(fmaxf(v.w, 0.f));
  }
  __shared__ int wcnt[32][4];
  __shared__ int pref[256];
  __shared__ unsigned cand[512];
  __shared__ float rr[8];

  // bit-descent: T = max{x : count(key < x) <= 512} = 513th smallest key
  unsigned T = 0;
  for (int b = 30; b >= 0; b--) {
    unsigned t = T | (1u << b);
    int c = 0;
#pragma unroll
    for (int j = 0; j < 32; j++) c += (key[j] < t) ? 1 : 0;
    for (int off = 32; off; off >>= 1) c += __shfl_down(c, off, 64);
    if ((tid & 63) == 0) wcnt[b][tid >> 6] = c;
    __syncthreads();
    int tot = wcnt[b][0] + wcnt[b][1] + wcnt[b][2] + wcnt[b][3];
    if (tot <= 512) T = t;
  }

  // gather strictly-less-than-T candidates (count c0 <= 512)
  int n_t = 0;
#pragma unroll
  for (int j = 0; j < 32; j++) n_t += (key[j] < T) ? 1 : 0;
  pref[tid] = n_t;
  __syncthreads();
  for (int s = 1; s < 256; s <<= 1) {
    int v = (tid >= s) ? pref[tid - s] : 0;
    __syncthreads();
    pref[tid] += v;
    __syncthreads();
  }
  int c0 = pref[255];
  int base = pref[tid] - n_t;
  cand[tid] = 0xFFFFFFFFu;
  cand[tid + 256] = 0xFFFFFFFFu;
  __syncthreads();
  {
    int idx = base;
#pragma unroll
    for (int j = 0; j < 32; j++)
      if (key[j] < T) cand[idx++] = key[j];
  }
  __syncthreads();

  // bitonic sort 512 ascending
  for (int k = 2; k <= 512; k <<= 1) {
    for (int j = k >> 1; j > 0; j >>= 1) {
      int i = ((tid & ~(j - 1)) << 1) | (tid & (j - 1));
      int p = i | j;
      bool up = (i & k) == 0;
      unsigned a = cand[i], b2 = cand[p];
      if ((a > b2) == up) { cand[i] = b2; cand[p] = a; }
      __syncthreads();
    }
  }

  // sorted 513-ascending = cand[0..c0) ++ (513-c0) copies of T; element 0 is the self (dropped)
  float d32  = sqrtf(__uint_as_float(32  < c0 ? cand[32]  : T));
  float d512 = sqrtf(__uint_as_float(512 < c0 ? cand[512] : T));
  int i1 = tid + 1, i2 = tid + 257;
  float di1 = sqrtf(__uint_as_float(i1 < c0 ? cand[i1] : T));
  float di2 = sqrtf(__uint_as_float(i2 < c0 ? cand[i2] : T));
  float s32 = (i1 <= 32) ? logf(di1 / d32 + 1e-12f) : 0.f;
  float s512 = logf(di1 / d512 + 1e-12f) + logf(di2 / d512 + 1e-12f);
  for (int off = 32; off; off >>= 1) {
    s32 += __shfl_down(s32, off, 64);
    s512 += __shfl_down(s512, off, 64);
  }
  if ((tid & 63) == 0) { rr[tid >> 6] = s32; rr[4 + (tid >> 6)] = s512; }
  __syncthreads();
  if (tid == 0) {
    float S32 = rr[0] + rr[1] + rr[2] + rr[3];
    float S512 = rr[4] + rr[5] + rr[6] + rr[7];
    out[OFF_L32 + r] = -32.f / S32;
    out[OFF_L512 + r] = -512.f / S512;
  }
}

// ---------------- logits = reshuffled z-gram / T (fp32 VALU; fallback path only) ----------------
__global__ __launch_bounds__(256) void zgram_logits_kernel(const float* __restrict__ zn,
                                                           float* __restrict__ out) {
  int bj = blockIdx.x, bi = blockIdx.y;
  const int ib = bi * 128, jb = bj * 128;
  const float* Ab = zn + (size_t)ib * DZ;
  const float* Bb = zn + (size_t)jb * DZ;

  __shared__ __attribute__((aligned(16))) float As[16][128];
  __shared__ __attribute__((aligned(16))) float Bs[16][128];

  int tid = threadIdx.x;
  int tx = tid & 15, ty = tid >> 4;
  int lrow = tid >> 1;
  int lk = (tid & 1) * 8;

  float acc[8][8];
#pragma unroll
  for (int i = 0; i < 8; i++)
#pragma unroll
    for (int j = 0; j < 8; j++) acc[i][j] = 0.f;

  for (int k0 = 0; k0 < DZ; k0 += 16) {
    float4 a0 = *(const float4*)(Ab + (size_t)lrow * DZ + k0 + lk);
    float4 a1 = *(const float4*)(Ab + (size_t)lrow * DZ + k0 + lk + 4);
    float4 b0 = *(const float4*)(Bb + (size_t)lrow * DZ + k0 + lk);
    float4 b1 = *(const float4*)(Bb + (size_t)lrow * DZ + k0 + lk + 4);
    __syncthreads();
    As[lk + 0][lrow] = a0.x; As[lk + 1][lrow] = a0.y; As[lk + 2][lrow] = a0.z; As[lk + 3][lrow] = a0.w;
    As[lk + 4][lrow] = a1.x; As[lk + 5][lrow] = a1.y; As[lk + 6][lrow] = a1.z; As[lk + 7][lrow] = a1.w;
    Bs[lk + 0][lrow] = b0.x; Bs[lk + 1][lrow] = b0.y; Bs[lk + 2][lrow] = b0.z; Bs[lk + 3][lrow] = b0.w;
    Bs[lk + 4][lrow] = b1.x; Bs[lk + 5][lrow] = b1.y; Bs[lk + 6][lrow] = b1.z; Bs[lk + 7][lrow] = b1.w;
    __syncthreads();
#pragma unroll
    for (int kk = 0; kk < 16; kk++) {
      float4 av0 = *(const float4*)&As[kk][ty * 8];
      float4 av1 = *(const float4*)&As[kk][ty * 8 + 4];
      float4 bv0 = *(const float4*)&Bs[kk][tx * 4];
      float4 bv1 = *(const float4*)&Bs[kk][tx * 4 + 64];
      float a_[8] = {av0.x, av0.y, av0.z, av0.w, av1.x, av1.y, av1.z, av1.w};
      float b_[8] = {bv0.x, bv0.y, bv0.z, bv0.w, bv1.x, bv1.y, bv1.z, bv1.w};
#pragma unroll
      for (int v = 0; v < 8; v++)
#pragma unroll
        for (int u = 0; u < 8; u++) acc[v][u] += a_[v] * b_[u];
    }
  }

#pragma unroll
  for (int v = 0; v < 8; v++) {
    int rrow = ib + ty * 8 + v;
#pragma unroll
    for (int u = 0; u < 8; u++) {
      int c = jb + tx * 4 + (u & 3) + (u >> 2) * 64;
      if (c == rrow) continue;
      float lg = 2.f * acc[v][u];  // /TEMPERATURE(0.5)
      int col;
      if (rrow < B_) col = (c >= B_) ? (c - B_) : (B_ + c - (c > rrow ? 1 : 0));
      else           col = (c < B_) ? c : (c - (c > rrow ? 1 : 0));
      out[OFF_LOGITS + (size_t)rrow * NL + col] = lg;
    }
  }
}

// ---------------- labels ----------------
__global__ void labels_kernel(float* __restrict__ out) {
  int i = blockIdx.x * 256 + threadIdx.x;
  if (i < N2) out[OFF_LAB + i] = (float)(i & (B_ - 1));
}

// ---------------- per-row loss: single-pass online softmax, float4, no LDS staging ----------------
// Row base (OFF_LOGITS + r*NL) is only 4B-aligned; read the aligned-float4 superset and mask
// out-of-row elements to -1e30 (neighbors are finite logits -> exp underflows to exactly 0).
__global__ __launch_bounds__(256) void loss_row_kernel(const float* __restrict__ out,
                                                       float* __restrict__ lossp) {
  int r = blockIdx.x, tid = threadIdx.x;
  const size_t base = OFF_LOGITS + (size_t)r * NL;       // float index of col 0
  const size_t a0 = base & ~(size_t)3;                   // aligned start
  const int head = (int)(base - a0);                     // 0..3
  const int nvec = (head + NL + 3) >> 2;                 // 2048 or 2049 float4s

  float m = -1e30f, s = 0.f;
  for (int j = tid; j < nvec; j += 256) {
    float4 v = *(const float4*)&out[a0 + (size_t)4 * j];
    int c0 = 4 * j - head;                               // col index of v.x
    float x0 = (unsigned)c0 < (unsigned)NL ? v.x : -1e30f;
    float x1 = (unsigned)(c0 + 1) < (unsigned)NL ? v.y : -1e30f;
    float x2 = (unsigned)(c0 + 2) < (unsigned)NL ? v.z : -1e30f;
    float x3 = (unsigned)(c0 + 3) < (unsigned)NL ? v.w : -1e30f;
    float vm = fmaxf(fmaxf(x0, x1), fmaxf(x2, x3));
    if (vm > m) { s *= expf(m - vm); m = vm; }
    s += expf(x0 - m) + expf(x1 - m) + expf(x2 - m) + expf(x3 - m);
  }
  // wave reduce (m, s)
  for (int off = 32; off; off >>= 1) {
    float mo = __shfl_down(m, off, 64);
    float so = __shfl_down(s, off, 64);
    float mn = fmaxf(m, mo);
    s = s * expf(m - mn) + so * expf(mo - mn);
    m = mn;
  }
  __shared__ float rm[4], rs[4];
  if ((tid & 63) == 0) { rm[tid >> 6] = m; rs[tid >> 6] = s; }
  __syncthreads();
  if (tid == 0) {
    float M = rm[0];
    float S = rs[0];
#pragma unroll
    for (int w = 1; w < 4; w++) {
      float mn = fmaxf(M, rm[w]);
      S = S * expf(M - mn) + rs[w] * expf(rm[w] - mn);
      M = mn;
    }
    lossp[r] = M + logf(S) - out[base + (r & (B_ - 1))];
  }
}

// ---------------- final mean ----------------
__global__ void finalize_kernel(const float* __restrict__ lossp, float* __restrict__ out) {
  int tid = threadIdx.x;
  float s = 0.f;
  for (int j = tid; j < N2; j += 256) s += lossp[j];
  for (int off = 32; off; off >>= 1) s += __shfl_down(s, off, 64);
  __shared__ float red[4];
  if ((tid & 63) == 0) red[tid >> 6] = s;
  __syncthreads();
  if (tid == 0) out[0] = (red[0] + red[1] + red[2] + red[3]) / (float)N2;
}

extern "C" void kernel_launch(void* const* d_in, const int* in_sizes, int n_in,
                              void* d_out, int out_size, void* d_ws, size_t ws_size,
                              hipStream_t stream) {
  const float* z0 = (const float*)d_in[0];
  const float* z1 = (const float*)d_in[1];
  const float* f0 = (const float*)d_in[2];
  const float* f1 = (const float*)d_in[3];
  float* out = (float*)d_out;
  float* ws = (float*)d_ws;
  float* zn = ws + WS_ZN;
  float* fn = ws + WS_FN;
  float* lp = ws + WS_LP;
  float* D2 = out;  // scratch overlay on d_out[0 .. N2*N2)

  const size_t need_bytes = ((size_t)WS_ZCOMB + (size_t)N2 * 128) * sizeof(float);  // ~75.4 MB
  dim3 g(64, 64);

  if (ws_size >= need_bytes) {
    unsigned short* fcomb = (unsigned short*)(ws + WS_FCOMB);
    unsigned short* zcomb = (unsigned short*)(ws + WS_ZCOMB);
    convert_kernel<<<N2, 256, 0, stream>>>(f0, f1, fcomb, fn);  // fuses fnorm
    znorm2_kernel<<<N2, 128, 0, stream>>>(z0, z1, zcomb);
    d2_gemm_pre_kernel<<<g, 256, 0, stream>>>(fcomb, fn, D2);
    select_lid_kernel<<<N2, 256, 0, stream>>>(D2, out);       // lids -> final slots (past D2)
    zgram_mfma_kernel<<<g, 256, 0, stream>>>(zcomb, out);     // overwrites D2 scratch with logits
  } else {
    fnorm_kernel<<<N2, 256, 0, stream>>>(f0, f1, fn);
    znorm_kernel<<<N2, 128, 0, stream>>>(z0, z1, zn);
    d2_gemm_mfma_kernel<<<g, 256, 0, stream>>>(f0, f1, fn, D2);
    select_lid_kernel<<<N2, 256, 0, stream>>>(D2, out);
    zgram_logits_kernel<<<g, 256, 0, stream>>>(zn, out);
  }

  labels_kernel<<<(N2 + 255) / 256, 256, 0, stream>>>(out);
  loss_row_kernel<<<N2, 256, 0, stream>>>(out, lp);
  finalize_kernel<<<1, 256, 0, stream>>>(lp, out);
}